// Round 7
// baseline (69315.179 us; speedup 1.0000x reference)
//
#include <hip/hip_runtime.h>

#define Bz 32
#define Tz 256
#define Hz 512
#define Nz 5
#define Rz 2
#define Wz 512
#define RWz 1024
#define XD 1536          // H + R*W
#define IFz 2573         // R*W + 3*W + 5*R + 3
#define EPSF 1e-6f
#define NWG 256
#define NT 1024
#define NTH (NWG*NT)     // 262144

// interleaved state layout: [kg][b][4] ; slab stride per kg = 32*4 = 128 floats
#define HSLAB 16384      // 128 kg * 128
#define RSLAB 32768      // 256 kg * 128

// workspace float offsets (keep host memset in sync!)
#define WXIT_OFF (Tz*HSLAB)                            // 4194304
#define WOUT_OFF (WXIT_OFF + IFz*Hz)                   // 5511680
#define HT_OFF   (WOUT_OFF + Hz*XD)                    // 6298112
#define CT_OFF   (HT_OFF + 2*HSLAB)                    // 6330880
#define RT_OFF   (CT_OFF + HSLAB)                      // 6347264
#define XIT_OFF  (RT_OFF + 2*RSLAB)                    // 6412800
#define MG_OFF   (XIT_OFF + IFz*Bz)                    // 6495136
#define UG_OFF   (MG_OFF + Bz*Nz*Wz)                   // 6577056
#define BAR_OFF  (UG_OFF + 1600 + 32)                  // 6578688 (64-aligned)

// xi field offsets
#define O_KR 0
#define O_BR 1024
#define O_KW 1026
#define O_BW 1538
#define O_E  1539
#define O_V  2051
#define O_FG 2563
#define O_GA 2565
#define O_GW 2566
#define O_PI 2567

__device__ __forceinline__ float sigf(float x){ return 1.0f/(1.0f+expf(-x)); }
__device__ __forceinline__ float splus(float x){ return fmaxf(x,0.0f) + log1pf(expf(-fabsf(x))); }

// ---- custom grid barrier ----
// bar[0..1023]: 16 counters at stride 64 (one 256B line each)
// bar[1024..2047]: 16 replicated generation flags at stride 64
__device__ __forceinline__ void gbar(unsigned* bar, unsigned k){
  __syncthreads();
  const int tid = threadIdx.x;
  const unsigned wg = blockIdx.x;
  if (tid == 0){
    __builtin_amdgcn_fence(__ATOMIC_RELEASE, "agent");
    __hip_atomic_fetch_add(&bar[(wg & 15u)*64], 1u, __ATOMIC_RELAXED, __HIP_MEMORY_SCOPE_AGENT);
  }
  if (wg == 0){
    if (tid < 16){
      const unsigned tgt = (NWG/16u)*(k+1u);
      while (__hip_atomic_load(&bar[tid*64], __ATOMIC_RELAXED, __HIP_MEMORY_SCOPE_AGENT) < tgt)
        __builtin_amdgcn_s_sleep(1);
    }
    __syncthreads();
    if (tid < 16){
      __builtin_amdgcn_fence(__ATOMIC_ACQ_REL, "agent");
      __hip_atomic_store(&bar[1024 + tid*64], k+1u, __ATOMIC_RELAXED, __HIP_MEMORY_SCOPE_AGENT);
    }
    __syncthreads();
  } else {
    if (tid == 0){
      while (__hip_atomic_load(&bar[1024 + (wg & 15u)*64], __ATOMIC_RELAXED, __HIP_MEMORY_SCOPE_AGENT) < k+1u)
        __builtin_amdgcn_s_sleep(1);
      __builtin_amdgcn_fence(__ATOMIC_ACQUIRE, "agent");
    }
    __syncthreads();
  }
}

// x: interleaved state, pre-offset by b*4; walks kg slabs (stride 128 floats)
// w: contiguous row. nkg = number of float4 groups.
__device__ __forceinline__ float dotI(const float* __restrict__ x,
                                      const float* __restrict__ w, int nkg){
  const float4* w4 = (const float4*)w;
  float a0=0.f,a1=0.f,a2=0.f,a3=0.f;
  #pragma unroll 8
  for (int kg=0; kg<nkg; kg++){
    float4 xv = *(const float4*)(x + (size_t)kg*128);
    float4 wv = w4[kg];
    a0 = fmaf(xv.x,wv.x,a0); a1 = fmaf(xv.y,wv.y,a1);
    a2 = fmaf(xv.z,wv.z,a2); a3 = fmaf(xv.w,wv.w,a3);
  }
  return (a0+a1)+(a2+a3);
}

__device__ void memops(int b, int t, const float* xiT,
                       float* Mg, float* ug, float* pg, float* wwg, float* Lg, float* wrg,
                       float* rT)
{
  __shared__ float s_xi[IFz];
  __shared__ float s_M[Nz*Wz];
  __shared__ float s_u[Nz], s_p[Nz], s_ww[Nz], s_a[Nz], s_L[Nz*Nz], s_wr[Rz*Nz];
  __shared__ float s_sc[13]; // 0:br0 1:br1 2:bw 3:fg0 4:fg1 5:ga 6:gw 7..12:pi
  __shared__ float s_m2[Nz], s_dt[Nz], s_d0[Nz], s_d1[Nz];
  __shared__ float s_kw2, s_kr2[2];
  __shared__ float s_fwd[Rz*Nz], s_bwd[Rz*Nz];

  const int tid = threadIdx.x;
  const int wv = tid >> 6, ln = tid & 63;

  for (int f = tid; f < IFz; f += NT) s_xi[f] = xiT[(size_t)b*IFz + f];
  for (int i = tid; i < Nz*Wz; i += NT) s_M[i] = Mg[(size_t)b*Nz*Wz + i];
  if (tid < Nz){ s_u[tid]=ug[b*Nz+tid]; s_p[tid]=pg[b*Nz+tid]; s_ww[tid]=wwg[b*Nz+tid]; }
  if (tid < Nz*Nz) s_L[tid] = Lg[b*Nz*Nz+tid];
  if (tid < Rz*Nz) s_wr[tid] = wrg[b*Rz*Nz+tid];
  __syncthreads();

  if (tid == 0){
    s_sc[0] = 1.0f + splus(s_xi[O_BR+0]);
    s_sc[1] = 1.0f + splus(s_xi[O_BR+1]);
    s_sc[2] = 1.0f + splus(s_xi[O_BW]);
    s_sc[3] = sigf(s_xi[O_FG+0]);
    s_sc[4] = sigf(s_xi[O_FG+1]);
    s_sc[5] = sigf(s_xi[O_GA]);
    s_sc[6] = sigf(s_xi[O_GW]);
    for (int r=0;r<Rz;r++){
      float x0=s_xi[O_PI+r*3+0], x1=s_xi[O_PI+r*3+1], x2=s_xi[O_PI+r*3+2];
      float m = fmaxf(x0,fmaxf(x1,x2));
      float e0=expf(x0-m), e1=expf(x1-m), e2=expf(x2-m);
      float s = e0+e1+e2;
      s_sc[7+r*3+0]=e0/s; s_sc[7+r*3+1]=e1/s; s_sc[7+r*3+2]=e2/s;
    }
  }
  __syncthreads();

  // psi & usage update (uses OLD ww, OLD wr)
  if (tid < Nz){
    float psi = (1.0f - s_sc[3]*s_wr[0*Nz+tid]) * (1.0f - s_sc[4]*s_wr[1*Nz+tid]);
    float uu = s_u[tid], w = s_ww[tid];
    s_u[tid] = (uu + w - uu*w) * psi;
  }

  // cosine(M_old, kw)
  if (wv < 4){
    const int n = wv;
    float pd=0.f, pm=0.f;
    for (int w = ln; w < Wz; w += 64){
      float kv = s_xi[O_KW+w], mv = s_M[n*Wz+w];
      pd = fmaf(kv,mv,pd); pm = fmaf(mv,mv,pm);
    }
    for (int off=32; off; off>>=1){ pd += __shfl_down(pd,off,64); pm += __shfl_down(pm,off,64); }
    if (ln==0){ s_dt[n]=pd; s_m2[n]=pm; }
  }
  if (wv == 3){
    float p2=0.f;
    for (int w=ln; w<Wz; w+=64){ float kv=s_xi[O_KW+w]; p2=fmaf(kv,kv,p2); }
    for (int off=32; off; off>>=1) p2 += __shfl_down(p2,off,64);
    if (ln==0) s_kw2 = p2;
  }
  __syncthreads();
  if (wv == 0){
    const int n = 4;
    float pd=0.f, pm=0.f;
    for (int w = ln; w < Wz; w += 64){
      float kv = s_xi[O_KW+w], mv = s_M[n*Wz+w];
      pd = fmaf(kv,mv,pd); pm = fmaf(mv,mv,pm);
    }
    for (int off=32; off; off>>=1){ pd += __shfl_down(pd,off,64); pm += __shfl_down(pm,off,64); }
    if (ln==0){ s_dt[n]=pd; s_m2[n]=pm; }
  }
  __syncthreads();

  if (tid == 0){
    // allocation weights from updated u (stable ascending argsort, N=5)
    float su[Nz]; int idx[Nz];
    for (int i=0;i<Nz;i++){
      float v = EPSF + (1.0f-EPSF)*s_u[i];
      int j=i;
      while (j>0 && su[j-1] > v){ su[j]=su[j-1]; idx[j]=idx[j-1]; j--; }
      su[j]=v; idx[j]=i;
    }
    float cp = 1.0f;
    for (int k=0;k<Nz;k++){ s_a[idx[k]] = (1.0f - su[k])*cp; cp *= su[k]; }
    // content write weights
    float rk = rsqrtf(s_kw2 + EPSF);
    float lg[Nz], mx=-1e30f;
    for (int n=0;n<Nz;n++){ lg[n] = s_sc[2]*s_dt[n]*rk*rsqrtf(s_m2[n]+EPSF); mx=fmaxf(mx,lg[n]); }
    float ssum=0.f;
    for (int n=0;n<Nz;n++){ lg[n]=expf(lg[n]-mx); ssum+=lg[n]; }
    float ga=s_sc[5], gw=s_sc[6];
    for (int n=0;n<Nz;n++){ float cwn = lg[n]/ssum; s_ww[n] = gw*(ga*s_a[n] + (1.0f-ga)*cwn); }
  }
  __syncthreads();

  // memory write
  for (int i = tid; i < Nz*Wz; i += NT){
    int n = i >> 9, w = i & 511;
    float e = sigf(s_xi[O_E+w]);
    float v = s_xi[O_V+w];
    s_M[i] = s_M[i]*(1.0f - s_ww[n]*e) + s_ww[n]*v;
  }
  __syncthreads();

  // link matrix, precedence, fwd/bwd
  if (tid == 0){
    float wsum = 0.f;
    for (int n=0;n<Nz;n++) wsum += s_ww[n];
    float Lo[Nz*Nz];
    for (int i=0;i<Nz;i++)
      for (int j=0;j<Nz;j++)
        Lo[i*Nz+j] = (i==j) ? 0.0f : ((1.0f - s_ww[i] - s_ww[j])*s_L[i*Nz+j] + s_ww[i]*s_p[j]);
    for (int i=0;i<Nz*Nz;i++) s_L[i]=Lo[i];
    for (int j=0;j<Nz;j++) s_p[j] = (1.0f-wsum)*s_p[j] + s_ww[j];
    for (int r=0;r<Rz;r++)
      for (int n=0;n<Nz;n++){
        float f=0.f, bb=0.f;
        for (int m=0;m<Nz;m++){ f = fmaf(s_L[n*Nz+m], s_wr[r*Nz+m], f); bb = fmaf(s_L[m*Nz+n], s_wr[r*Nz+m], bb); }
        s_fwd[r*Nz+n]=f; s_bwd[r*Nz+n]=bb;
      }
  }
  __syncthreads();

  // cosine(M_new, kr)
  if (wv < 4){
    const int n = wv;
    float pm=0.f,p0=0.f,p1=0.f;
    for (int w=ln; w<Wz; w+=64){
      float mv=s_M[n*Wz+w];
      pm=fmaf(mv,mv,pm);
      p0=fmaf(s_xi[O_KR+w],    mv,p0);
      p1=fmaf(s_xi[O_KR+Wz+w], mv,p1);
    }
    for (int off=32; off; off>>=1){
      pm += __shfl_down(pm,off,64); p0 += __shfl_down(p0,off,64); p1 += __shfl_down(p1,off,64);
    }
    if (ln==0){ s_m2[n]=pm; s_d0[n]=p0; s_d1[n]=p1; }
  }
  __syncthreads();
  if (wv == 0){
    const int n = 4;
    float pm=0.f,p0=0.f,p1=0.f;
    for (int w=ln; w<Wz; w+=64){
      float mv=s_M[n*Wz+w];
      pm=fmaf(mv,mv,pm);
      p0=fmaf(s_xi[O_KR+w],    mv,p0);
      p1=fmaf(s_xi[O_KR+Wz+w], mv,p1);
    }
    for (int off=32; off; off>>=1){
      pm += __shfl_down(pm,off,64); p0 += __shfl_down(p0,off,64); p1 += __shfl_down(p1,off,64);
    }
    if (ln==0){ s_m2[n]=pm; s_d0[n]=p0; s_d1[n]=p1; }
  } else if (wv == 1 || wv == 2){
    const int r = wv - 1;
    float p2=0.f;
    for (int w=ln; w<Wz; w+=64){ float kv=s_xi[O_KR+r*Wz+w]; p2=fmaf(kv,kv,p2); }
    for (int off=32; off; off>>=1) p2 += __shfl_down(p2,off,64);
    if (ln==0) s_kr2[r]=p2;
  }
  __syncthreads();

  if (tid == 0){
    for (int r=0;r<Rz;r++){
      float rk = rsqrtf(s_kr2[r]+EPSF);
      const float* dd = (r==0) ? s_d0 : s_d1;
      float br = s_sc[r];
      float lg[Nz], mx=-1e30f;
      for (int n=0;n<Nz;n++){ lg[n] = br*dd[n]*rk*rsqrtf(s_m2[n]+EPSF); mx=fmaxf(mx,lg[n]); }
      float ssum=0.f;
      for (int n=0;n<Nz;n++){ lg[n]=expf(lg[n]-mx); ssum+=lg[n]; }
      for (int n=0;n<Nz;n++){
        float crn = lg[n]/ssum;
        s_wr[r*Nz+n] = s_sc[7+r*3+0]*s_bwd[r*Nz+n] + s_sc[7+r*3+1]*crn + s_sc[7+r*3+2]*s_fwd[r*Nz+n];
      }
    }
  }
  __syncthreads();

  // read vectors (write interleaved [kg][b][4]) + state writeback
  float* rbase = rT + (size_t)((t+1)&1)*RSLAB;
  for (int w = tid; w < Wz; w += NT){
    float m0=s_M[0*Wz+w], m1=s_M[1*Wz+w], m2=s_M[2*Wz+w], m3=s_M[3*Wz+w], m4=s_M[4*Wz+w];
    #pragma unroll
    for (int r=0;r<Rz;r++){
      float rv = s_wr[r*Nz+0]*m0 + s_wr[r*Nz+1]*m1 + s_wr[r*Nz+2]*m2
               + s_wr[r*Nz+3]*m3 + s_wr[r*Nz+4]*m4;
      int i = r*Wz + w;
      rbase[(size_t)(i>>2)*128 + b*4 + (i&3)] = rv;
    }
  }
  for (int i = tid; i < Nz*Wz; i += NT) Mg[(size_t)b*Nz*Wz+i] = s_M[i];
  if (tid < Nz){ ug[b*Nz+tid]=s_u[tid]; pg[b*Nz+tid]=s_p[tid]; wwg[b*Nz+tid]=s_ww[tid]; }
  if (tid < Nz*Nz) Lg[b*Nz*Nz+tid]=s_L[tid];
  if (tid < Rz*Nz) wrg[b*Rz*Nz+tid]=s_wr[tid];
}

__global__ void __launch_bounds__(NT, 4)
dnc_kernel(const int* __restrict__ src, const float* __restrict__ emb,
           const float* __restrict__ w_ih, const float* __restrict__ w_hh,
           const float* __restrict__ b_lstm,
           const float* __restrict__ w_xi, const float* __restrict__ b_xi,
           const float* __restrict__ w_out, const float* __restrict__ b_out,
           float* __restrict__ out, float* __restrict__ ws)
{
  const int tid = threadIdx.x;
  const int gid = blockIdx.x*NT + tid;

  float* embT  = ws;                       // [T][128 kg][32 b][4]
  float* wxiT  = ws + WXIT_OFF;            // [IF][H]
  float* woutT = ws + WOUT_OFF;            // [H][XD]
  float* hT    = ws + HT_OFF;              // [2][128][32][4]
  float* cT    = ws + CT_OFF;              // [128][32][4]
  float* rT    = ws + RT_OFF;              // [2][256][32][4]
  float* xiT   = ws + XIT_OFF;             // [B][IF]
  float* Mg    = ws + MG_OFF;              // [B][N][W]
  float* ug    = ws + UG_OFF;              // [B][N]
  float* pg    = ug + Bz*Nz;
  float* wwg   = pg + Bz*Nz;
  float* Lg    = wwg + Bz*Nz;              // [B][N*N]
  float* wrg   = Lg + Bz*Nz*Nz;            // [B][R*N]
  unsigned* bar = (unsigned*)(ws + BAR_OFF);
  unsigned kbar = 0;

  // ---- phase 0: init / transposes / embedding gather (interleaved) ----
  {
    float4* embT4 = (float4*)embT;
    const float4* emb4 = (const float4*)emb;
    for (int i = gid; i < Tz*128*Bz; i += NTH){   // i = t*4096 + kg*32 + b
      int b = i & 31, kg = (i>>5) & 127, tt = i >> 12;
      embT4[i] = emb4[(size_t)src[b*Tz+tt]*128 + kg];
    }
  }
  for (size_t i = gid; i < (size_t)IFz*Hz; i += NTH){
    int k = (int)(i % Hz); size_t f = i / Hz;
    wxiT[i] = w_xi[(size_t)k*IFz + f];
  }
  for (size_t i = gid; i < (size_t)Hz*XD; i += NTH){
    int k = (int)(i % XD); int j = (int)(i / XD);
    woutT[i] = w_out[(size_t)k*Hz + j];
  }
  for (int i = gid; i < 2*HSLAB; i += NTH) hT[i]=0.f;
  for (int i = gid; i < HSLAB;   i += NTH) cT[i]=0.f;
  for (int i = gid; i < 2*RSLAB; i += NTH) rT[i]=0.f;
  for (int i = gid; i < Bz*Nz*Wz;i += NTH) Mg[i]=0.f;
  for (int i = gid; i < Bz*(3*Nz + Nz*Nz + Rz*Nz); i += NTH) ug[i]=0.f; // ug..wrg contiguous
  gbar(bar, kbar); kbar++;

  // ---- time loop ----
  for (int t = 0; t < Tz; ++t){
    const int cur = t & 1, nxt = (t+1)&1;

    // Phase A: gates GEMV, 4-way K-split. gid = j(9b) | b(5b) | gate(2b) | ks(2b)
    // WG blk covers j in {2blk, 2blk+1} -> 8 weight rows (64KB), pinned across steps.
    {
      const int ks   = gid & 3;
      const int gate = (gid >> 2) & 3;
      const int b    = (gid >> 4) & 31;
      const int j    = gid >> 9;
      const int row  = gate*Hz + j;
      const int b4   = b*4;
      const float* xp; const float* wp;
      if (ks == 0){      xp = embT + (size_t)t*HSLAB + b4;           wp = w_ih + (size_t)row*XD; }
      else if (ks == 1){ xp = rT + (size_t)cur*RSLAB + b4;           wp = w_ih + (size_t)row*XD + Hz; }
      else if (ks == 2){ xp = rT + (size_t)cur*RSLAB + 128*128 + b4; wp = w_ih + (size_t)row*XD + 2*Hz; }
      else {             xp = hT + (size_t)cur*HSLAB + b4;           wp = w_hh + (size_t)row*Hz; }
      float acc = dotI(xp, wp, 128);
      acc += __shfl_xor(acc, 1, 64);
      acc += __shfl_xor(acc, 2, 64);
      acc += b_lstm[row];
      const int lane = tid & 63;
      const int bse  = lane & ~12;      // zero gate bits [2:3]
      float gi = __shfl(acc, bse+0,  64);
      float gf = __shfl(acc, bse+4,  64);
      float gg = __shfl(acc, bse+8,  64);
      float go = __shfl(acc, bse+12, 64);
      if ((lane & 15) == 0){            // ks==0 && gate==0
        const int ca = (j>>2)*128 + b4 + (j&3);
        float cv = cT[ca];
        float cn = sigf(gf)*cv + sigf(gi)*tanhf(gg);
        float hn = sigf(go)*tanhf(cn);
        cT[ca] = cn;
        hT[(size_t)nxt*HSLAB + ca] = hn;
      }
    }
    gbar(bar, kbar); kbar++;

    // Phase B: xi = h_new @ w_xi + b_xi, 2-way K-split.
    // gid = f(12b) | b(5b) | ks(1b); WG owns 16 f-rows, pinned.
    {
      const float* hb = hT + (size_t)nxt*HSLAB;
      const int ks = gid & 1;
      const int b  = (gid >> 1) & 31;
      const int f  = gid >> 6;
      if (f < IFz){
        float acc = dotI(hb + b*4 + ks*64*128, wxiT + (size_t)f*Hz + ks*256, 64);
        acc += __shfl_xor(acc, 1, 64);
        if (ks == 0) xiT[(size_t)b*IFz + f] = acc + b_xi[f];
      }
    }
    gbar(bar, kbar); kbar++;

    // Phase C: WGs 0..31 memops; WGs 32+ compute out(t-1) with 2-way K-split
    if (blockIdx.x < Bz){
      memops(blockIdx.x, t, xiT, Mg, ug, pg, wwg, Lg, wrg, rT);
    } else if (t > 0){
      const int id = (blockIdx.x - Bz)*NT + tid;
      if (id < 2*Hz*Bz){
        const int ks = id & 1;
        const int o  = id >> 1;
        const int b  = o & 31;
        const int j  = o >> 5;
        const float* wj = woutT + (size_t)j*XD;
        const float* hc = hT + (size_t)cur*HSLAB;
        const float* rc = rT + (size_t)cur*RSLAB;
        float acc;
        if (ks == 0) acc = dotI(hc + b*4, wj, 128) + dotI(rc + b*4, wj + Hz, 64);
        else         acc = dotI(rc + 64*128 + b*4, wj + Hz + 256, 192);
        acc += __shfl_xor(acc, 1, 64);
        if (ks == 0)
          out[(size_t)b*Tz*Hz + (size_t)(t-1)*Hz + j] = acc + b_out[j];
      }
    }
    gbar(bar, kbar); kbar++;
  }

  // ---- epilogue: out(T-1) (state in buffer 0), final h and c ----
  if (gid < 2*Hz*Bz){
    const int ks = gid & 1;
    const int o  = gid >> 1;
    const int b  = o & 31;
    const int j  = o >> 5;
    const float* wj = woutT + (size_t)j*XD;
    float acc;
    if (ks == 0) acc = dotI(hT + b*4, wj, 128) + dotI(rT + b*4, wj + Hz, 64);
    else         acc = dotI(rT + 64*128 + b*4, wj + Hz + 256, 192);
    acc += __shfl_xor(acc, 1, 64);
    if (ks == 0)
      out[(size_t)b*Tz*Hz + (size_t)(Tz-1)*Hz + j] = acc + b_out[j];
  }
  if (gid < Hz*Bz){
    const int b = gid & 31, j = gid >> 5;
    const int ca = (j>>2)*128 + b*4 + (j&3);
    out[(size_t)Bz*Tz*Hz + (size_t)b*Hz + j]                 = hT[ca];
    out[(size_t)Bz*Tz*Hz + (size_t)Bz*Hz + (size_t)b*Hz + j] = cT[ca];
  }
}

extern "C" void kernel_launch(void* const* d_in, const int* in_sizes, int n_in,
                              void* d_out, int out_size, void* d_ws, size_t ws_size,
                              hipStream_t stream)
{
  const int*   src    = (const int*)  d_in[0];
  // d_in[1] = source_lengths (unused by reference)
  const float* emb    = (const float*)d_in[2];
  const float* w_ih   = (const float*)d_in[3];
  const float* w_hh   = (const float*)d_in[4];
  const float* b_lstm = (const float*)d_in[5];
  const float* w_xi   = (const float*)d_in[6];
  const float* b_xi   = (const float*)d_in[7];
  const float* w_out  = (const float*)d_in[8];
  const float* b_out  = (const float*)d_in[9];
  float* out = (float*)d_out;
  float* ws  = (float*)d_ws;

  // zero the barrier region (16 counters + 16 flags, stride-64) each call:
  // deterministic across graph replays, stream-ordered, capture-safe.
  hipMemsetAsync((char*)d_ws + (size_t)BAR_OFF*4, 0, 8192, stream);

  void* args[] = { &src, &emb, &w_ih, &w_hh, &b_lstm, &w_xi, &b_xi, &w_out, &b_out, &out, &ws };
  hipLaunchCooperativeKernel((const void*)dnc_kernel, dim3(NWG), dim3(NT), args, 0, stream);
}

// Round 8
// 43581.860 us; speedup vs baseline: 1.5905x; 1.5905x over previous
//
#include <hip/hip_runtime.h>

#define Bz 32
#define Tz 256
#define Hz 512
#define Nz 5
#define Rz 2
#define Wz 512
#define RWz 1024
#define XD 1536          // H + R*W
#define IFz 2573         // R*W + 3*W + 5*R + 3
#define EPSF 1e-6f
#define NWG 256
#define NT 256
#define NTH (NWG*NT)     // 65536

// interleaved state layout: [kg][b][4] ; slab stride per kg = 32*4 = 128 floats
#define HSLAB 16384      // 128 kg * 128
#define RSLAB 32768      // 256 kg * 128

// workspace float offsets
#define WXIT_OFF (Tz*HSLAB)                            // 4194304
#define WOUT_OFF (WXIT_OFF + IFz*Hz)                   // 5511680
#define HT_OFF   (WOUT_OFF + Hz*XD)                    // 6298112
#define CT_OFF   (HT_OFF + 2*HSLAB)                    // 6330880
#define RT_OFF   (CT_OFF + HSLAB)                      // 6347264
#define XIT_OFF  (RT_OFF + 2*RSLAB)                    // 6412800
#define MG_OFF   (XIT_OFF + IFz*Bz)                    // 6495136
#define UG_OFF   (MG_OFF + Bz*Nz*Wz)                   // 6577056
#define BAR_OFF  (UG_OFF + 1600 + 32)                  // 6578688 (64-aligned)

// xi field offsets
#define O_KR 0
#define O_BR 1024
#define O_KW 1026
#define O_BW 1538
#define O_E  1539
#define O_V  2051
#define O_FG 2563
#define O_GA 2565
#define O_GW 2566
#define O_PI 2567

typedef unsigned long long u64;

__device__ __forceinline__ float sigf(float x){ return 1.0f/(1.0f+expf(-x)); }
__device__ __forceinline__ float splus(float x){ return fmaxf(x,0.0f) + log1pf(expf(-fabsf(x))); }

// bypass (coherent, sc0 sc1) accessors for cross-WG state — no fences needed
__device__ __forceinline__ void stage64(float* dst_lds, const float* src){
  u64 v = __hip_atomic_load((const u64*)src, __ATOMIC_RELAXED, __HIP_MEMORY_SCOPE_AGENT);
  *(u64*)dst_lds = v;
}
__device__ __forceinline__ float ld32cv(const float* p){
  return __hip_atomic_load(p, __ATOMIC_RELAXED, __HIP_MEMORY_SCOPE_AGENT);
}
__device__ __forceinline__ void st32cv(float* p, float v){
  __hip_atomic_store(p, v, __ATOMIC_RELAXED, __HIP_MEMORY_SCOPE_AGENT);
}

// ---- grid barriers ----
// bar[0..1023]: 16 counters stride 64; bar[1024..2047]: 16 replicated gen flags
// fenced version: full agent release/acquire (L2 wb+inv) — init & final only
__device__ __forceinline__ void gbar_fence(unsigned* bar, unsigned k){
  __syncthreads();
  const int tid = threadIdx.x;
  const unsigned wg = blockIdx.x;
  if (tid == 0){
    __builtin_amdgcn_fence(__ATOMIC_RELEASE, "agent");
    __hip_atomic_fetch_add(&bar[(wg & 15u)*64], 1u, __ATOMIC_RELAXED, __HIP_MEMORY_SCOPE_AGENT);
  }
  if (wg == 0){
    if (tid < 16){
      const unsigned tgt = (NWG/16u)*(k+1u);
      while (__hip_atomic_load(&bar[tid*64], __ATOMIC_RELAXED, __HIP_MEMORY_SCOPE_AGENT) < tgt)
        __builtin_amdgcn_s_sleep(1);
    }
    __syncthreads();
    if (tid < 16){
      __builtin_amdgcn_fence(__ATOMIC_ACQ_REL, "agent");
      __hip_atomic_store(&bar[1024 + tid*64], k+1u, __ATOMIC_RELAXED, __HIP_MEMORY_SCOPE_AGENT);
    }
    __syncthreads();
  } else {
    if (tid == 0){
      while (__hip_atomic_load(&bar[1024 + (wg & 15u)*64], __ATOMIC_RELAXED, __HIP_MEMORY_SCOPE_AGENT) < k+1u)
        __builtin_amdgcn_s_sleep(1);
      __builtin_amdgcn_fence(__ATOMIC_ACQUIRE, "agent");
    }
    __syncthreads();
  }
}
// no-fence version: cross-WG data travels via sc0/sc1 bypass ops (already at
// the coherence point); only need vmcnt-drain before arrival. L2 stays warm.
__device__ __forceinline__ void gbar_nf(unsigned* bar, unsigned k){
  __syncthreads();   // compiler drains vmcnt/lgkmcnt before s_barrier
  const int tid = threadIdx.x;
  const unsigned wg = blockIdx.x;
  if (tid == 0){
    asm volatile("s_waitcnt vmcnt(0) lgkmcnt(0)" ::: "memory");
    __hip_atomic_fetch_add(&bar[(wg & 15u)*64], 1u, __ATOMIC_RELAXED, __HIP_MEMORY_SCOPE_AGENT);
  }
  if (wg == 0){
    if (tid < 16){
      const unsigned tgt = (NWG/16u)*(k+1u);
      while (__hip_atomic_load(&bar[tid*64], __ATOMIC_RELAXED, __HIP_MEMORY_SCOPE_AGENT) < tgt)
        __builtin_amdgcn_s_sleep(1);
    }
    __syncthreads();
    if (tid < 16)
      __hip_atomic_store(&bar[1024 + tid*64], k+1u, __ATOMIC_RELAXED, __HIP_MEMORY_SCOPE_AGENT);
    __syncthreads();
  } else {
    if (tid == 0){
      while (__hip_atomic_load(&bar[1024 + (wg & 15u)*64], __ATOMIC_RELAXED, __HIP_MEMORY_SCOPE_AGENT) < k+1u)
        __builtin_amdgcn_s_sleep(1);
    }
    __syncthreads();
  }
}

// global interleaved dot: x pre-offset by b*4, slab stride 128 floats (cached)
__device__ __forceinline__ float dotI(const float* __restrict__ x,
                                      const float* __restrict__ w, int nkg){
  const float4* w4 = (const float4*)w;
  float a0=0.f,a1=0.f,a2=0.f,a3=0.f;
  #pragma unroll 8
  for (int kg=0; kg<nkg; kg++){
    float4 xv = *(const float4*)(x + (size_t)kg*128);
    float4 wv = w4[kg];
    a0 = fmaf(xv.x,wv.x,a0); a1 = fmaf(xv.y,wv.y,a1);
    a2 = fmaf(xv.z,wv.z,a2); a3 = fmaf(xv.w,wv.w,a3);
  }
  return (a0+a1)+(a2+a3);
}
// LDS dot: xl pre-offset by b_local*4, slab stride `stride` floats
__device__ __forceinline__ float dotL(const float* xl, int stride,
                                      const float* __restrict__ w, int nkg){
  const float4* w4 = (const float4*)w;
  float a0=0.f,a1=0.f,a2=0.f,a3=0.f;
  #pragma unroll 8
  for (int kg=0; kg<nkg; kg++){
    float4 xv = *(const float4*)(xl + kg*stride);
    float4 wv = w4[kg];
    a0 = fmaf(xv.x,wv.x,a0); a1 = fmaf(xv.y,wv.y,a1);
    a2 = fmaf(xv.z,wv.z,a2); a3 = fmaf(xv.w,wv.w,a3);
  }
  return (a0+a1)+(a2+a3);
}

__device__ void memops(int b, int t, const float* xiT,
                       float* Mg, float* ug, float* pg, float* wwg, float* Lg, float* wrg,
                       float* rT)
{
  __shared__ float s_xi[IFz];
  __shared__ float s_M[Nz*Wz];
  __shared__ float s_u[Nz], s_p[Nz], s_ww[Nz], s_a[Nz], s_L[Nz*Nz], s_wr[Rz*Nz];
  __shared__ float s_sc[13];
  __shared__ float s_m2[Nz], s_dt[Nz], s_d0[Nz], s_d1[Nz];
  __shared__ float s_kw2, s_kr2[2];
  __shared__ float s_fwd[Rz*Nz], s_bwd[Rz*Nz];

  const int tid = threadIdx.x;
  const int wv = tid >> 6, ln = tid & 63;

  for (int f = tid; f < IFz; f += NT) s_xi[f] = ld32cv(&xiT[(size_t)b*IFz + f]); // cross-WG: bypass
  for (int i = tid; i < Nz*Wz; i += NT) s_M[i] = Mg[(size_t)b*Nz*Wz + i];        // WG-private: cached
  if (tid < Nz){ s_u[tid]=ug[b*Nz+tid]; s_p[tid]=pg[b*Nz+tid]; s_ww[tid]=wwg[b*Nz+tid]; }
  if (tid < Nz*Nz) s_L[tid] = Lg[b*Nz*Nz+tid];
  if (tid < Rz*Nz) s_wr[tid] = wrg[b*Rz*Nz+tid];
  __syncthreads();

  if (tid == 0){
    s_sc[0] = 1.0f + splus(s_xi[O_BR+0]);
    s_sc[1] = 1.0f + splus(s_xi[O_BR+1]);
    s_sc[2] = 1.0f + splus(s_xi[O_BW]);
    s_sc[3] = sigf(s_xi[O_FG+0]);
    s_sc[4] = sigf(s_xi[O_FG+1]);
    s_sc[5] = sigf(s_xi[O_GA]);
    s_sc[6] = sigf(s_xi[O_GW]);
    for (int r=0;r<Rz;r++){
      float x0=s_xi[O_PI+r*3+0], x1=s_xi[O_PI+r*3+1], x2=s_xi[O_PI+r*3+2];
      float m = fmaxf(x0,fmaxf(x1,x2));
      float e0=expf(x0-m), e1=expf(x1-m), e2=expf(x2-m);
      float s = e0+e1+e2;
      s_sc[7+r*3+0]=e0/s; s_sc[7+r*3+1]=e1/s; s_sc[7+r*3+2]=e2/s;
    }
  }
  __syncthreads();

  if (tid < Nz){
    float psi = (1.0f - s_sc[3]*s_wr[0*Nz+tid]) * (1.0f - s_sc[4]*s_wr[1*Nz+tid]);
    float uu = s_u[tid], w = s_ww[tid];
    s_u[tid] = (uu + w - uu*w) * psi;
  }

  // cosine(M_old, kw)
  if (wv < 4){
    const int n = wv;
    float pd=0.f, pm=0.f;
    for (int w = ln; w < Wz; w += 64){
      float kv = s_xi[O_KW+w], mv = s_M[n*Wz+w];
      pd = fmaf(kv,mv,pd); pm = fmaf(mv,mv,pm);
    }
    for (int off=32; off; off>>=1){ pd += __shfl_down(pd,off,64); pm += __shfl_down(pm,off,64); }
    if (ln==0){ s_dt[n]=pd; s_m2[n]=pm; }
  }
  if (wv == 3){
    float p2=0.f;
    for (int w=ln; w<Wz; w+=64){ float kv=s_xi[O_KW+w]; p2=fmaf(kv,kv,p2); }
    for (int off=32; off; off>>=1) p2 += __shfl_down(p2,off,64);
    if (ln==0) s_kw2 = p2;
  }
  __syncthreads();
  if (wv == 0){
    const int n = 4;
    float pd=0.f, pm=0.f;
    for (int w = ln; w < Wz; w += 64){
      float kv = s_xi[O_KW+w], mv = s_M[n*Wz+w];
      pd = fmaf(kv,mv,pd); pm = fmaf(mv,mv,pm);
    }
    for (int off=32; off; off>>=1){ pd += __shfl_down(pd,off,64); pm += __shfl_down(pm,off,64); }
    if (ln==0){ s_dt[n]=pd; s_m2[n]=pm; }
  }
  __syncthreads();

  if (tid == 0){
    float su[Nz]; int idx[Nz];
    for (int i=0;i<Nz;i++){
      float v = EPSF + (1.0f-EPSF)*s_u[i];
      int j=i;
      while (j>0 && su[j-1] > v){ su[j]=su[j-1]; idx[j]=idx[j-1]; j--; }
      su[j]=v; idx[j]=i;
    }
    float cp = 1.0f;
    for (int k=0;k<Nz;k++){ s_a[idx[k]] = (1.0f - su[k])*cp; cp *= su[k]; }
    float rk = rsqrtf(s_kw2 + EPSF);
    float lg[Nz], mx=-1e30f;
    for (int n=0;n<Nz;n++){ lg[n] = s_sc[2]*s_dt[n]*rk*rsqrtf(s_m2[n]+EPSF); mx=fmaxf(mx,lg[n]); }
    float ssum=0.f;
    for (int n=0;n<Nz;n++){ lg[n]=expf(lg[n]-mx); ssum+=lg[n]; }
    float ga=s_sc[5], gw=s_sc[6];
    for (int n=0;n<Nz;n++){ float cwn = lg[n]/ssum; s_ww[n] = gw*(ga*s_a[n] + (1.0f-ga)*cwn); }
  }
  __syncthreads();

  for (int i = tid; i < Nz*Wz; i += NT){
    int n = i >> 9, w = i & 511;
    float e = sigf(s_xi[O_E+w]);
    float v = s_xi[O_V+w];
    s_M[i] = s_M[i]*(1.0f - s_ww[n]*e) + s_ww[n]*v;
  }
  __syncthreads();

  if (tid == 0){
    float wsum = 0.f;
    for (int n=0;n<Nz;n++) wsum += s_ww[n];
    float Lo[Nz*Nz];
    for (int i=0;i<Nz;i++)
      for (int j=0;j<Nz;j++)
        Lo[i*Nz+j] = (i==j) ? 0.0f : ((1.0f - s_ww[i] - s_ww[j])*s_L[i*Nz+j] + s_ww[i]*s_p[j]);
    for (int i=0;i<Nz*Nz;i++) s_L[i]=Lo[i];
    for (int j=0;j<Nz;j++) s_p[j] = (1.0f-wsum)*s_p[j] + s_ww[j];
    for (int r=0;r<Rz;r++)
      for (int n=0;n<Nz;n++){
        float f=0.f, bb=0.f;
        for (int m=0;m<Nz;m++){ f = fmaf(s_L[n*Nz+m], s_wr[r*Nz+m], f); bb = fmaf(s_L[m*Nz+n], s_wr[r*Nz+m], bb); }
        s_fwd[r*Nz+n]=f; s_bwd[r*Nz+n]=bb;
      }
  }
  __syncthreads();

  // cosine(M_new, kr)
  if (wv < 4){
    const int n = wv;
    float pm=0.f,p0=0.f,p1=0.f;
    for (int w=ln; w<Wz; w+=64){
      float mv=s_M[n*Wz+w];
      pm=fmaf(mv,mv,pm);
      p0=fmaf(s_xi[O_KR+w],    mv,p0);
      p1=fmaf(s_xi[O_KR+Wz+w], mv,p1);
    }
    for (int off=32; off; off>>=1){
      pm += __shfl_down(pm,off,64); p0 += __shfl_down(p0,off,64); p1 += __shfl_down(p1,off,64);
    }
    if (ln==0){ s_m2[n]=pm; s_d0[n]=p0; s_d1[n]=p1; }
  }
  __syncthreads();
  if (wv == 0){
    const int n = 4;
    float pm=0.f,p0=0.f,p1=0.f;
    for (int w=ln; w<Wz; w+=64){
      float mv=s_M[n*Wz+w];
      pm=fmaf(mv,mv,pm);
      p0=fmaf(s_xi[O_KR+w],    mv,p0);
      p1=fmaf(s_xi[O_KR+Wz+w], mv,p1);
    }
    for (int off=32; off; off>>=1){
      pm += __shfl_down(pm,off,64); p0 += __shfl_down(p0,off,64); p1 += __shfl_down(p1,off,64);
    }
    if (ln==0){ s_m2[n]=pm; s_d0[n]=p0; s_d1[n]=p1; }
  } else if (wv == 1 || wv == 2){
    const int r = wv - 1;
    float p2=0.f;
    for (int w=ln; w<Wz; w+=64){ float kv=s_xi[O_KR+r*Wz+w]; p2=fmaf(kv,kv,p2); }
    for (int off=32; off; off>>=1) p2 += __shfl_down(p2,off,64);
    if (ln==0) s_kr2[r]=p2;
  }
  __syncthreads();

  if (tid == 0){
    for (int r=0;r<Rz;r++){
      float rk = rsqrtf(s_kr2[r]+EPSF);
      const float* dd = (r==0) ? s_d0 : s_d1;
      float br = s_sc[r];
      float lg[Nz], mx=-1e30f;
      for (int n=0;n<Nz;n++){ lg[n] = br*dd[n]*rk*rsqrtf(s_m2[n]+EPSF); mx=fmaxf(mx,lg[n]); }
      float ssum=0.f;
      for (int n=0;n<Nz;n++){ lg[n]=expf(lg[n]-mx); ssum+=lg[n]; }
      for (int n=0;n<Nz;n++){
        float crn = lg[n]/ssum;
        s_wr[r*Nz+n] = s_sc[7+r*3+0]*s_bwd[r*Nz+n] + s_sc[7+r*3+1]*crn + s_sc[7+r*3+2]*s_fwd[r*Nz+n];
      }
    }
  }
  __syncthreads();

  // read vectors -> rT (cross-WG: bypass stores) + private state writeback (cached)
  float* rbase = rT + (size_t)((t+1)&1)*RSLAB;
  for (int w = tid; w < Wz; w += NT){
    float m0=s_M[0*Wz+w], m1=s_M[1*Wz+w], m2=s_M[2*Wz+w], m3=s_M[3*Wz+w], m4=s_M[4*Wz+w];
    #pragma unroll
    for (int r=0;r<Rz;r++){
      float rv = s_wr[r*Nz+0]*m0 + s_wr[r*Nz+1]*m1 + s_wr[r*Nz+2]*m2
               + s_wr[r*Nz+3]*m3 + s_wr[r*Nz+4]*m4;
      int i = r*Wz + w;
      st32cv(&rbase[(size_t)(i>>2)*128 + b*4 + (i&3)], rv);
    }
  }
  for (int i = tid; i < Nz*Wz; i += NT) Mg[(size_t)b*Nz*Wz+i] = s_M[i];
  if (tid < Nz){ ug[b*Nz+tid]=s_u[tid]; pg[b*Nz+tid]=s_p[tid]; wwg[b*Nz+tid]=s_ww[tid]; }
  if (tid < Nz*Nz) Lg[b*Nz*Nz+tid]=s_L[tid];
  if (tid < Rz*Nz) wrg[b*Rz*Nz+tid]=s_wr[tid];
}

__global__ void __launch_bounds__(NT, 1)
dnc_kernel(const int* __restrict__ src, const float* __restrict__ emb,
           const float* __restrict__ w_ih, const float* __restrict__ w_hh,
           const float* __restrict__ b_lstm,
           const float* __restrict__ w_xi, const float* __restrict__ b_xi,
           const float* __restrict__ w_out, const float* __restrict__ b_out,
           float* __restrict__ out, float* __restrict__ ws)
{
  __shared__ __align__(16) float s_x[24576];   // 96 KB staging for r/h slices

  const int tid = threadIdx.x;
  const int gid = blockIdx.x*NT + tid;

  float* embT  = ws;                       // [T][128 kg][32 b][4]   (cached, RO after init)
  float* wxiT  = ws + WXIT_OFF;            // [IF][H]                (cached, RO)
  float* woutT = ws + WOUT_OFF;            // [H][XD]                (cached, RO)
  float* hT    = ws + HT_OFF;              // [2][128][32][4]        (bypass, cross-WG)
  float* cT    = ws + CT_OFF;              // [128][32][4]           (cached, WG-private)
  float* rT    = ws + RT_OFF;              // [2][256][32][4]        (bypass, cross-WG)
  float* xiT   = ws + XIT_OFF;             // [B][IF]                (bypass, cross-WG)
  float* Mg    = ws + MG_OFF;              // [B][N][W]              (cached, WG-private)
  float* ug    = ws + UG_OFF;
  float* pg    = ug + Bz*Nz;
  float* wwg   = pg + Bz*Nz;
  float* Lg    = wwg + Bz*Nz;
  float* wrg   = Lg + Bz*Nz*Nz;
  unsigned* bar = (unsigned*)(ws + BAR_OFF);
  unsigned kbar = 0;

  // ---- phase 0: init / transposes / embedding gather ----
  {
    float4* embT4 = (float4*)embT;
    const float4* emb4 = (const float4*)emb;
    for (int i = gid; i < Tz*128*Bz; i += NTH){
      int b = i & 31, kg = (i>>5) & 127, tt = i >> 12;
      embT4[i] = emb4[(size_t)src[b*Tz+tt]*128 + kg];
    }
  }
  for (size_t i = gid; i < (size_t)IFz*Hz; i += NTH){
    int k = (int)(i % Hz); size_t f = i / Hz;
    wxiT[i] = w_xi[(size_t)k*IFz + f];
  }
  for (size_t i = gid; i < (size_t)Hz*XD; i += NTH){
    int k = (int)(i % XD); int j = (int)(i / XD);
    woutT[i] = w_out[(size_t)k*Hz + j];
  }
  for (int i = gid; i < 2*HSLAB; i += NTH) hT[i]=0.f;
  for (int i = gid; i < HSLAB;   i += NTH) cT[i]=0.f;
  for (int i = gid; i < 2*RSLAB; i += NTH) rT[i]=0.f;
  for (int i = gid; i < Bz*Nz*Wz;i += NTH) Mg[i]=0.f;
  for (int i = gid; i < Bz*(3*Nz + Nz*Nz + Rz*Nz); i += NTH) ug[i]=0.f;
  gbar_fence(bar, kbar); kbar++;   // full fence: flush init writes, inv all caches

  // ---- time loop (no cache-invalidating fences inside) ----
  for (int t = 0; t < Tz; ++t){
    const int cur = t & 1, nxt = (t+1)&1;

    // Phase A: WG = (jq, b-half). Stage r[cur],h[cur] for 16 b into LDS (bypass),
    // weights stream from (now genuinely resident) L2.
    {
      const int jq = blockIdx.x >> 1;
      const int b0 = (blockIdx.x & 1) << 4;
      const float* rsrc = rT + (size_t)cur*RSLAB;
      const float* hsrc = hT + (size_t)cur*HSLAB;
      for (int u = tid; u < 12288; u += NT){
        if (u < 8192){
          int kg = u >> 5, rem = u & 31, bl = rem >> 1, hf = rem & 1;
          stage64(s_x + kg*64 + bl*4 + hf*2, rsrc + kg*128 + (b0+bl)*4 + hf*2);
        } else {
          int u2 = u - 8192;
          int kg = u2 >> 5, rem = u2 & 31, bl = rem >> 1, hf = rem & 1;
          stage64(s_x + 16384 + kg*64 + bl*4 + hf*2, hsrc + kg*128 + (b0+bl)*4 + hf*2);
        }
      }
      __syncthreads();
      const int gate = tid & 3;
      const int bl   = (tid >> 2) & 15;
      const int b    = b0 + bl;
      const int j    = 4*jq + (tid >> 6);
      const int row  = gate*Hz + j;
      const float* w1 = w_ih + (size_t)row*XD;
      const float* w2 = w_hh + (size_t)row*Hz;
      float acc = dotI(embT + (size_t)t*HSLAB + b*4, w1, 128)
                + dotL(s_x + bl*4,         64, w1 + Hz, 256)
                + dotL(s_x + 16384 + bl*4, 64, w2,      128)
                + b_lstm[row];
      const int lane = tid & 63;
      const int bse  = lane & ~3;
      float gi = __shfl(acc, bse+0, 64);
      float gf = __shfl(acc, bse+1, 64);
      float gg = __shfl(acc, bse+2, 64);
      float go = __shfl(acc, bse+3, 64);
      if (gate == 0){
        const int ca = (j>>2)*128 + b*4 + (j&3);
        float cv = cT[ca];
        float cn = sigf(gf)*cv + sigf(gi)*tanhf(gg);
        float hn = sigf(go)*tanhf(cn);
        cT[ca] = cn;
        st32cv(&hT[(size_t)nxt*HSLAB + ca], hn);
      }
    }
    gbar_nf(bar, kbar); kbar++;

    // Phase B: stage ALL h_new (64 KB) into LDS (bypass); xi stores bypass.
    {
      const float* hb = hT + (size_t)nxt*HSLAB;
      for (int u = tid; u < 8192; u += NT)
        stage64(s_x + u*2, hb + u*2);
      __syncthreads();
      for (int id = gid; id < IFz*Bz; id += NTH){
        const int b = id & 31, f = id >> 5;
        float acc = dotL(s_x + b*4, 128, wxiT + (size_t)f*Hz, 128);
        st32cv(&xiT[(size_t)b*IFz + f], acc + b_xi[f]);
      }
    }
    gbar_nf(bar, kbar); kbar++;

    // Phase C: WGs 0..31 memops; WGs 32..159 out(t-1) with staged h/r
    if (blockIdx.x < Bz){
      memops(blockIdx.x, t, xiT, Mg, ug, pg, wwg, Lg, wrg, rT);
    } else if (blockIdx.x < 160 && t > 0){
      const int idx = blockIdx.x - Bz;       // 0..127
      const int jg  = idx >> 1;              // 0..63 -> j in [8jg, 8jg+8)
      const int b0  = (idx & 1) << 4;
      const float* rsrc = rT + (size_t)cur*RSLAB;
      const float* hsrc = hT + (size_t)cur*HSLAB;
      for (int u = tid; u < 12288; u += NT){
        if (u < 8192){
          int kg = u >> 5, rem = u & 31, bl = rem >> 1, hf = rem & 1;
          stage64(s_x + kg*64 + bl*4 + hf*2, rsrc + kg*128 + (b0+bl)*4 + hf*2);
        } else {
          int u2 = u - 8192;
          int kg = u2 >> 5, rem = u2 & 31, bl = rem >> 1, hf = rem & 1;
          stage64(s_x + 16384 + kg*64 + bl*4 + hf*2, hsrc + kg*128 + (b0+bl)*4 + hf*2);
        }
      }
      __syncthreads();
      const int bl = tid & 15;
      const int ks = (tid >> 4) & 1;
      const int j  = 8*jg + (tid >> 5);
      const int b  = b0 + bl;
      const float* wj = woutT + (size_t)j*XD;
      float acc;
      if (ks == 0) acc = dotL(s_x + 16384 + bl*4, 64, wj,          128)   // h . w[0:512]
                       + dotL(s_x + bl*4,         64, wj + Hz,      64);  // r[0:256]
      else         acc = dotL(s_x + 64*64 + bl*4, 64, wj + Hz+256, 192);  // r[256:1024]
      acc += __shfl_xor(acc, 16, 64);
      if (ks == 0)
        out[(size_t)b*Tz*Hz + (size_t)(t-1)*Hz + j] = acc + b_out[j];
    }
    gbar_nf(bar, kbar); kbar++;
  }

  gbar_fence(bar, kbar); kbar++;   // full fence: make bypass state + cT visible to cached reads

  // ---- epilogue: out(T-1) (state in buffer 0), final h and c ----
  if (gid < 2*Hz*Bz){
    const int ks = gid & 1;
    const int o  = gid >> 1;
    const int b  = o & 31;
    const int j  = o >> 5;
    const float* wj = woutT + (size_t)j*XD;
    float acc;
    if (ks == 0) acc = dotI(hT + b*4, wj, 128) + dotI(rT + b*4, wj + Hz, 64);
    else         acc = dotI(rT + 64*128 + b*4, wj + Hz + 256, 192);
    acc += __shfl_xor(acc, 1, 64);
    if (ks == 0)
      out[(size_t)b*Tz*Hz + (size_t)(Tz-1)*Hz + j] = acc + b_out[j];
  }
  if (gid < Hz*Bz){
    const int b = gid & 31, j = gid >> 5;
    const int ca = (j>>2)*128 + b*4 + (j&3);
    out[(size_t)Bz*Tz*Hz + (size_t)b*Hz + j]                 = hT[ca];
    out[(size_t)Bz*Tz*Hz + (size_t)Bz*Hz + (size_t)b*Hz + j] = cT[ca];
  }
}

extern "C" void kernel_launch(void* const* d_in, const int* in_sizes, int n_in,
                              void* d_out, int out_size, void* d_ws, size_t ws_size,
                              hipStream_t stream)
{
  const int*   src    = (const int*)  d_in[0];
  // d_in[1] = source_lengths (unused by reference)
  const float* emb    = (const float*)d_in[2];
  const float* w_ih   = (const float*)d_in[3];
  const float* w_hh   = (const float*)d_in[4];
  const float* b_lstm = (const float*)d_in[5];
  const float* w_xi   = (const float*)d_in[6];
  const float* b_xi   = (const float*)d_in[7];
  const float* w_out  = (const float*)d_in[8];
  const float* b_out  = (const float*)d_in[9];
  float* out = (float*)d_out;
  float* ws  = (float*)d_ws;

  // zero barrier region (16 counters + 16 flags, stride-64) each call
  hipMemsetAsync((char*)d_ws + (size_t)BAR_OFF*4, 0, 8192, stream);

  void* args[] = { &src, &emb, &w_ih, &w_hh, &b_lstm, &w_xi, &b_xi, &w_out, &b_out, &out, &ws };
  hipLaunchCooperativeKernel((const void*)dnc_kernel, dim3(NWG), dim3(NT), args, 0, stream);
}

// Round 10
// 37773.230 us; speedup vs baseline: 1.8350x; 1.1538x over previous
//
#include <hip/hip_runtime.h>

#define Bz 32
#define Tz 256
#define Hz 512
#define Nz 5
#define Rz 2
#define Wz 512
#define RWz 1024
#define XD 1536          // H + R*W
#define IFz 2573
#define EPSF 1e-6f
#define NWG 256
#define NT 1024
#define NTH (NWG*NT)     // 262144

// interleaved state layout: [kg][b][4] ; slab stride per kg = 32*4 = 128 floats
#define HSLAB 16384      // 128 kg * 128
#define RSLAB 32768      // 256 kg * 128

// workspace float offsets (identical to R7 run)
#define WXIT_OFF (Tz*HSLAB)                            // 4194304
#define WOUT_OFF (WXIT_OFF + IFz*Hz)                   // 5511680
#define HT_OFF   (WOUT_OFF + Hz*XD)                    // 6298112
#define CT_OFF   (HT_OFF + 2*HSLAB)                    // 6330880
#define RT_OFF   (CT_OFF + HSLAB)                      // 6347264
#define XIT_OFF  (RT_OFF + 2*RSLAB)                    // 6412800
#define MG_OFF   (XIT_OFF + IFz*Bz)                    // 6495136
#define UG_OFF   (MG_OFF + Bz*Nz*Wz)                   // 6577056
#define BAR_OFF  (UG_OFF + 1600 + 32)                  // 6578688 (64-aligned)

// xi field offsets
#define O_KR 0
#define O_BR 1024
#define O_KW 1026
#define O_BW 1538
#define O_E  1539
#define O_V  2051
#define O_FG 2563
#define O_GA 2565
#define O_GW 2566
#define O_PI 2567

typedef unsigned long long u64;

__device__ __forceinline__ float sigf(float x){ return 1.0f/(1.0f+expf(-x)); }
__device__ __forceinline__ float splus(float x){ return fmaxf(x,0.0f) + log1pf(expf(-fabsf(x))); }

// coherent accessors for cross-WG state (proven in R7)
__device__ __forceinline__ void stage64(float* dst_lds, const float* src){
  u64 v = __hip_atomic_load((const u64*)src, __ATOMIC_RELAXED, __HIP_MEMORY_SCOPE_AGENT);
  *(u64*)dst_lds = v;
}
__device__ __forceinline__ float ld32cv(const float* p){
  return __hip_atomic_load(p, __ATOMIC_RELAXED, __HIP_MEMORY_SCOPE_AGENT);
}
__device__ __forceinline__ void st32cv(float* p, float v){
  __hip_atomic_store(p, v, __ATOMIC_RELAXED, __HIP_MEMORY_SCOPE_AGENT);
}

// ---- grid barriers (verbatim from R7 run) ----
__device__ __forceinline__ void gbar_fence(unsigned* bar, unsigned k){
  __syncthreads();
  const int tid = threadIdx.x;
  const unsigned wg = blockIdx.x;
  if (tid == 0){
    __builtin_amdgcn_fence(__ATOMIC_RELEASE, "agent");
    __hip_atomic_fetch_add(&bar[(wg & 15u)*64], 1u, __ATOMIC_RELAXED, __HIP_MEMORY_SCOPE_AGENT);
  }
  if (wg == 0){
    if (tid < 16){
      const unsigned tgt = (NWG/16u)*(k+1u);
      while (__hip_atomic_load(&bar[tid*64], __ATOMIC_RELAXED, __HIP_MEMORY_SCOPE_AGENT) < tgt)
        __builtin_amdgcn_s_sleep(1);
    }
    __syncthreads();
    if (tid < 16){
      __builtin_amdgcn_fence(__ATOMIC_ACQ_REL, "agent");
      __hip_atomic_store(&bar[1024 + tid*64], k+1u, __ATOMIC_RELAXED, __HIP_MEMORY_SCOPE_AGENT);
    }
    __syncthreads();
  } else {
    if (tid == 0){
      while (__hip_atomic_load(&bar[1024 + (wg & 15u)*64], __ATOMIC_RELAXED, __HIP_MEMORY_SCOPE_AGENT) < k+1u)
        __builtin_amdgcn_s_sleep(1);
      __builtin_amdgcn_fence(__ATOMIC_ACQUIRE, "agent");
    }
    __syncthreads();
  }
}
__device__ __forceinline__ void gbar_nf(unsigned* bar, unsigned k){
  __syncthreads();
  const int tid = threadIdx.x;
  const unsigned wg = blockIdx.x;
  if (tid == 0){
    asm volatile("s_waitcnt vmcnt(0) lgkmcnt(0)" ::: "memory");
    __hip_atomic_fetch_add(&bar[(wg & 15u)*64], 1u, __ATOMIC_RELAXED, __HIP_MEMORY_SCOPE_AGENT);
  }
  if (wg == 0){
    if (tid < 16){
      const unsigned tgt = (NWG/16u)*(k+1u);
      while (__hip_atomic_load(&bar[tid*64], __ATOMIC_RELAXED, __HIP_MEMORY_SCOPE_AGENT) < tgt)
        __builtin_amdgcn_s_sleep(1);
    }
    __syncthreads();
    if (tid < 16)
      __hip_atomic_store(&bar[1024 + tid*64], k+1u, __ATOMIC_RELAXED, __HIP_MEMORY_SCOPE_AGENT);
    __syncthreads();
  } else {
    if (tid == 0){
      while (__hip_atomic_load(&bar[1024 + (wg & 15u)*64], __ATOMIC_RELAXED, __HIP_MEMORY_SCOPE_AGENT) < k+1u)
        __builtin_amdgcn_s_sleep(1);
    }
    __syncthreads();
  }
}

// global interleaved dot: x pre-offset by b*4, slab stride 128 floats (cached)
__device__ __forceinline__ float dotI(const float* __restrict__ x,
                                      const float* __restrict__ w, int nkg){
  const float4* w4 = (const float4*)w;
  float a0=0.f,a1=0.f,a2=0.f,a3=0.f;
  #pragma unroll 8
  for (int kg=0; kg<nkg; kg++){
    float4 xv = *(const float4*)(x + (size_t)kg*128);
    float4 wv = w4[kg];
    a0 = fmaf(xv.x,wv.x,a0); a1 = fmaf(xv.y,wv.y,a1);
    a2 = fmaf(xv.z,wv.z,a2); a3 = fmaf(xv.w,wv.w,a3);
  }
  return (a0+a1)+(a2+a3);
}
// LDS dot: xl pre-offset by b_local*4, slab stride `stride` floats
__device__ __forceinline__ float dotL(const float* xl, int stride,
                                      const float* __restrict__ w, int nkg){
  const float4* w4 = (const float4*)w;
  float a0=0.f,a1=0.f,a2=0.f,a3=0.f;
  #pragma unroll 8
  for (int kg=0; kg<nkg; kg++){
    float4 xv = *(const float4*)(xl + kg*stride);
    float4 wv = w4[kg];
    a0 = fmaf(xv.x,wv.x,a0); a1 = fmaf(xv.y,wv.y,a1);
    a2 = fmaf(xv.z,wv.z,a2); a3 = fmaf(xv.w,wv.w,a3);
  }
  return (a0+a1)+(a2+a3);
}

__device__ void memops(int b, int t, const float* xiT,
                       float* Mg, float* ug, float* pg, float* wwg, float* Lg, float* wrg,
                       float* rT)
{
  __shared__ float s_xi[IFz];
  __shared__ float s_M[Nz*Wz];
  __shared__ float s_u[Nz], s_p[Nz], s_ww[Nz], s_a[Nz], s_L[Nz*Nz], s_wr[Rz*Nz];
  __shared__ float s_sc[13];
  __shared__ float s_m2[Nz], s_dt[Nz], s_d0[Nz], s_d1[Nz];
  __shared__ float s_kw2, s_kr2[2];
  __shared__ float s_fwd[Rz*Nz], s_bwd[Rz*Nz];

  const int tid = threadIdx.x;
  const int wv = tid >> 6, ln = tid & 63;

  for (int f = tid; f < IFz; f += NT) s_xi[f] = ld32cv(&xiT[(size_t)b*IFz + f]);
  for (int i = tid; i < Nz*Wz; i += NT) s_M[i] = Mg[(size_t)b*Nz*Wz + i];
  if (tid < Nz){ s_u[tid]=ug[b*Nz+tid]; s_p[tid]=pg[b*Nz+tid]; s_ww[tid]=wwg[b*Nz+tid]; }
  if (tid < Nz*Nz) s_L[tid] = Lg[b*Nz*Nz+tid];
  if (tid < Rz*Nz) s_wr[tid] = wrg[b*Rz*Nz+tid];
  __syncthreads();

  if (tid == 0){
    s_sc[0] = 1.0f + splus(s_xi[O_BR+0]);
    s_sc[1] = 1.0f + splus(s_xi[O_BR+1]);
    s_sc[2] = 1.0f + splus(s_xi[O_BW]);
    s_sc[3] = sigf(s_xi[O_FG+0]);
    s_sc[4] = sigf(s_xi[O_FG+1]);
    s_sc[5] = sigf(s_xi[O_GA]);
    s_sc[6] = sigf(s_xi[O_GW]);
    for (int r=0;r<Rz;r++){
      float x0=s_xi[O_PI+r*3+0], x1=s_xi[O_PI+r*3+1], x2=s_xi[O_PI+r*3+2];
      float m = fmaxf(x0,fmaxf(x1,x2));
      float e0=expf(x0-m), e1=expf(x1-m), e2=expf(x2-m);
      float s = e0+e1+e2;
      s_sc[7+r*3+0]=e0/s; s_sc[7+r*3+1]=e1/s; s_sc[7+r*3+2]=e2/s;
    }
  }
  __syncthreads();

  if (tid < Nz){
    float psi = (1.0f - s_sc[3]*s_wr[0*Nz+tid]) * (1.0f - s_sc[4]*s_wr[1*Nz+tid]);
    float uu = s_u[tid], w = s_ww[tid];
    s_u[tid] = (uu + w - uu*w) * psi;
  }

  // cosine(M_old, kw)
  if (wv < 4){
    const int n = wv;
    float pd=0.f, pm=0.f;
    for (int w = ln; w < Wz; w += 64){
      float kv = s_xi[O_KW+w], mv = s_M[n*Wz+w];
      pd = fmaf(kv,mv,pd); pm = fmaf(mv,mv,pm);
    }
    for (int off=32; off; off>>=1){ pd += __shfl_down(pd,off,64); pm += __shfl_down(pm,off,64); }
    if (ln==0){ s_dt[n]=pd; s_m2[n]=pm; }
  }
  if (wv == 3){
    float p2=0.f;
    for (int w=ln; w<Wz; w+=64){ float kv=s_xi[O_KW+w]; p2=fmaf(kv,kv,p2); }
    for (int off=32; off; off>>=1) p2 += __shfl_down(p2,off,64);
    if (ln==0) s_kw2 = p2;
  }
  __syncthreads();
  if (wv == 0){
    const int n = 4;
    float pd=0.f, pm=0.f;
    for (int w = ln; w < Wz; w += 64){
      float kv = s_xi[O_KW+w], mv = s_M[n*Wz+w];
      pd = fmaf(kv,mv,pd); pm = fmaf(mv,mv,pm);
    }
    for (int off=32; off; off>>=1){ pd += __shfl_down(pd,off,64); pm += __shfl_down(pm,off,64); }
    if (ln==0){ s_dt[n]=pd; s_m2[n]=pm; }
  }
  __syncthreads();

  if (tid == 0){
    float su[Nz]; int idx[Nz];
    for (int i=0;i<Nz;i++){
      float v = EPSF + (1.0f-EPSF)*s_u[i];
      int j=i;
      while (j>0 && su[j-1] > v){ su[j]=su[j-1]; idx[j]=idx[j-1]; j--; }
      su[j]=v; idx[j]=i;
    }
    float cp = 1.0f;
    for (int k=0;k<Nz;k++){ s_a[idx[k]] = (1.0f - su[k])*cp; cp *= su[k]; }
    float rk = rsqrtf(s_kw2 + EPSF);
    float lg[Nz], mx=-1e30f;
    for (int n=0;n<Nz;n++){ lg[n] = s_sc[2]*s_dt[n]*rk*rsqrtf(s_m2[n]+EPSF); mx=fmaxf(mx,lg[n]); }
    float ssum=0.f;
    for (int n=0;n<Nz;n++){ lg[n]=expf(lg[n]-mx); ssum+=lg[n]; }
    float ga=s_sc[5], gw=s_sc[6];
    for (int n=0;n<Nz;n++){ float cwn = lg[n]/ssum; s_ww[n] = gw*(ga*s_a[n] + (1.0f-ga)*cwn); }
  }
  __syncthreads();

  for (int i = tid; i < Nz*Wz; i += NT){
    int n = i >> 9, w = i & 511;
    float e = sigf(s_xi[O_E+w]);
    float v = s_xi[O_V+w];
    s_M[i] = s_M[i]*(1.0f - s_ww[n]*e) + s_ww[n]*v;
  }
  __syncthreads();

  if (tid == 0){
    float wsum = 0.f;
    for (int n=0;n<Nz;n++) wsum += s_ww[n];
    float Lo[Nz*Nz];
    for (int i=0;i<Nz;i++)
      for (int j=0;j<Nz;j++)
        Lo[i*Nz+j] = (i==j) ? 0.0f : ((1.0f - s_ww[i] - s_ww[j])*s_L[i*Nz+j] + s_ww[i]*s_p[j]);
    for (int i=0;i<Nz*Nz;i++) s_L[i]=Lo[i];
    for (int j=0;j<Nz;j++) s_p[j] = (1.0f-wsum)*s_p[j] + s_ww[j];
    for (int r=0;r<Rz;r++)
      for (int n=0;n<Nz;n++){
        float f=0.f, bb=0.f;
        for (int m=0;m<Nz;m++){ f = fmaf(s_L[n*Nz+m], s_wr[r*Nz+m], f); bb = fmaf(s_L[m*Nz+n], s_wr[r*Nz+m], bb); }
        s_fwd[r*Nz+n]=f; s_bwd[r*Nz+n]=bb;
      }
  }
  __syncthreads();

  // cosine(M_new, kr)
  if (wv < 4){
    const int n = wv;
    float pm=0.f,p0=0.f,p1=0.f;
    for (int w=ln; w<Wz; w+=64){
      float mv=s_M[n*Wz+w];
      pm=fmaf(mv,mv,pm);
      p0=fmaf(s_xi[O_KR+w],    mv,p0);
      p1=fmaf(s_xi[O_KR+Wz+w], mv,p1);
    }
    for (int off=32; off; off>>=1){
      pm += __shfl_down(pm,off,64); p0 += __shfl_down(p0,off,64); p1 += __shfl_down(p1,off,64);
    }
    if (ln==0){ s_m2[n]=pm; s_d0[n]=p0; s_d1[n]=p1; }
  }
  __syncthreads();
  if (wv == 0){
    const int n = 4;
    float pm=0.f,p0=0.f,p1=0.f;
    for (int w=ln; w<Wz; w+=64){
      float mv=s_M[n*Wz+w];
      pm=fmaf(mv,mv,pm);
      p0=fmaf(s_xi[O_KR+w],    mv,p0);
      p1=fmaf(s_xi[O_KR+Wz+w], mv,p1);
    }
    for (int off=32; off; off>>=1){
      pm += __shfl_down(pm,off,64); p0 += __shfl_down(p0,off,64); p1 += __shfl_down(p1,off,64);
    }
    if (ln==0){ s_m2[n]=pm; s_d0[n]=p0; s_d1[n]=p1; }
  } else if (wv == 1 || wv == 2){
    const int r = wv - 1;
    float p2=0.f;
    for (int w=ln; w<Wz; w+=64){ float kv=s_xi[O_KR+r*Wz+w]; p2=fmaf(kv,kv,p2); }
    for (int off=32; off; off>>=1) p2 += __shfl_down(p2,off,64);
    if (ln==0) s_kr2[r]=p2;
  }
  __syncthreads();

  if (tid == 0){
    for (int r=0;r<Rz;r++){
      float rk = rsqrtf(s_kr2[r]+EPSF);
      const float* dd = (r==0) ? s_d0 : s_d1;
      float br = s_sc[r];
      float lg[Nz], mx=-1e30f;
      for (int n=0;n<Nz;n++){ lg[n] = br*dd[n]*rk*rsqrtf(s_m2[n]+EPSF); mx=fmaxf(mx,lg[n]); }
      float ssum=0.f;
      for (int n=0;n<Nz;n++){ lg[n]=expf(lg[n]-mx); ssum+=lg[n]; }
      for (int n=0;n<Nz;n++){
        float crn = lg[n]/ssum;
        s_wr[r*Nz+n] = s_sc[7+r*3+0]*s_bwd[r*Nz+n] + s_sc[7+r*3+1]*crn + s_sc[7+r*3+2]*s_fwd[r*Nz+n];
      }
    }
  }
  __syncthreads();

  // read vectors -> rT interleaved (coherent stores) + private state (cached)
  float* rbase = rT + (size_t)((t+1)&1)*RSLAB;
  for (int w = tid; w < Wz; w += NT){
    float m0=s_M[0*Wz+w], m1=s_M[1*Wz+w], m2=s_M[2*Wz+w], m3=s_M[3*Wz+w], m4=s_M[4*Wz+w];
    #pragma unroll
    for (int r=0;r<Rz;r++){
      float rv = s_wr[r*Nz+0]*m0 + s_wr[r*Nz+1]*m1 + s_wr[r*Nz+2]*m2
               + s_wr[r*Nz+3]*m3 + s_wr[r*Nz+4]*m4;
      int i = r*Wz + w;
      st32cv(&rbase[(size_t)(i>>2)*128 + b*4 + (i&3)], rv);
    }
  }
  for (int i = tid; i < Nz*Wz; i += NT) Mg[(size_t)b*Nz*Wz+i] = s_M[i];
  if (tid < Nz){ ug[b*Nz+tid]=s_u[tid]; pg[b*Nz+tid]=s_p[tid]; wwg[b*Nz+tid]=s_ww[tid]; }
  if (tid < Nz*Nz) Lg[b*Nz*Nz+tid]=s_L[tid];
  if (tid < Rz*Nz) wrg[b*Rz*Nz+tid]=s_wr[tid];
}

__global__ void __launch_bounds__(NT, 4)
dnc_kernel(const int* __restrict__ src, const float* __restrict__ emb,
           const float* __restrict__ w_ih, const float* __restrict__ w_hh,
           const float* __restrict__ b_lstm,
           const float* __restrict__ w_xi, const float* __restrict__ b_xi,
           const float* __restrict__ w_out, const float* __restrict__ b_out,
           float* __restrict__ out, float* __restrict__ ws)
{
  __shared__ __align__(16) float s_x[6144];   // 24 KB: per-quad state staging

  const int tid = threadIdx.x;
  const int gid = blockIdx.x*NT + tid;

  float* embT  = ws;                       // [T][128kg][32b][4]  cached RO
  float* wxiT  = ws + WXIT_OFF;            // [IF][512]           cached RO
  float* woutT = ws + WOUT_OFF;            // [512][1536]         cached RO
  float* hT    = ws + HT_OFF;              // [2][128][32][4]     coherent
  float* cT    = ws + CT_OFF;              // [128][32][4]        cached, WG-pinned
  float* rT    = ws + RT_OFF;              // [2][256][32][4]     coherent
  float* xiT   = ws + XIT_OFF;             // [B][IFz]            coherent
  float* Mg    = ws + MG_OFF;              // [B][2560]           cached, WG-pinned
  float* ug    = ws + UG_OFF;
  float* pg    = ug + Bz*Nz;
  float* wwg   = pg + Bz*Nz;
  float* Lg    = wwg + Bz*Nz;
  float* wrg   = Lg + Bz*Nz*Nz;
  unsigned* bar = (unsigned*)(ws + BAR_OFF);
  unsigned kbar = 0;

  // ---- init (R7-verbatim loops, NTH-strided) ----
  {
    float4* embT4 = (float4*)embT;
    const float4* emb4 = (const float4*)emb;
    for (int i = gid; i < Tz*128*Bz; i += NTH){
      int b = i & 31, kg = (i>>5) & 127, tt = i >> 12;
      embT4[i] = emb4[(size_t)src[b*Tz+tt]*128 + kg];
    }
  }
  for (size_t i = gid; i < (size_t)IFz*Hz; i += NTH){
    int k = (int)(i % Hz); size_t f = i / Hz;
    wxiT[i] = w_xi[(size_t)k*IFz + f];
  }
  for (size_t i = gid; i < (size_t)Hz*XD; i += NTH){
    int k = (int)(i % XD); int j = (int)(i / XD);
    woutT[i] = w_out[(size_t)k*Hz + j];
  }
  for (int i = gid; i < 2*HSLAB; i += NTH) hT[i]=0.f;
  for (int i = gid; i < HSLAB;   i += NTH) cT[i]=0.f;
  for (int i = gid; i < 2*RSLAB; i += NTH) rT[i]=0.f;
  for (int i = gid; i < Bz*Nz*Wz;i += NTH) Mg[i]=0.f;
  for (int i = gid; i < Bz*(3*Nz + Nz*Nz + Rz*Nz); i += NTH) ug[i]=0.f;
  gbar_fence(bar, kbar); kbar++;

  const int q  = blockIdx.x >> 5;   // 0..7  batch-quad
  const int ch = blockIdx.x & 31;   // 0..31 row-chunk
  const int b0 = q*4;

  // ---- time loop (no agent fences inside) ----
  for (int t = 0; t < Tz; ++t){
    const int cur = t & 1, nxt = (t+1)&1;

    // ===== Phase A: gates GEMV. WG=(q,ch): 16 j x 4 gates x 4 b, K-split-4 =====
    {
      const float* rsrc = rT + (size_t)cur*RSLAB;
      const float* hsrc = hT + (size_t)cur*HSLAB;
      for (int u = tid; u < 3072; u += NT){
        if (u < 2048){
          int kg = u >> 3, rem = u & 7, bi = rem >> 1, hf = rem & 1;
          stage64(s_x + kg*16 + bi*4 + hf*2, rsrc + kg*128 + (b0+bi)*4 + hf*2);
        } else {
          int u2 = u - 2048;
          int kg = u2 >> 3, rem = u2 & 7, bi = rem >> 1, hf = rem & 1;
          stage64(s_x + 4096 + kg*16 + bi*4 + hf*2, hsrc + kg*128 + (b0+bi)*4 + hf*2);
        }
      }
      __syncthreads();
      const int ks   = tid & 3;
      const int gate = (tid >> 2) & 3;
      const int bb   = (tid >> 4) & 3;
      const int jj   = tid >> 6;            // 0..15
      const int j    = ch*16 + jj;
      const int row  = gate*Hz + j;
      const int b    = b0 + bb;
      float acc;
      if (ks == 0)      acc = dotI(embT + (size_t)t*HSLAB + b*4, w_ih + (size_t)row*XD, 128);
      else if (ks == 1) acc = dotL(s_x + bb*4,           16, w_ih + (size_t)row*XD + 512,  128);
      else if (ks == 2) acc = dotL(s_x + 2048 + bb*4,    16, w_ih + (size_t)row*XD + 1024, 128);
      else              acc = dotL(s_x + 4096 + bb*4,    16, w_hh + (size_t)row*Hz,        128);
      acc += __shfl_xor(acc, 1, 64);
      acc += __shfl_xor(acc, 2, 64);
      acc += b_lstm[row];
      // lane bits: 0-1 ks, 2-3 gate, 4-5 bb
      const int lane = tid & 63;
      const int base = lane & ~12;
      float gi = __shfl(acc, base+0,  64);
      float gf = __shfl(acc, base+4,  64);
      float gg = __shfl(acc, base+8,  64);
      float go = __shfl(acc, base+12, 64);
      if ((lane & 15) == 0){                // ks==0 && gate==0
        const int ca = (j>>2)*128 + b*4 + (j&3);
        float cv = cT[ca];
        float cn = sigf(gf)*cv + sigf(gi)*tanhf(gg);
        float hn = sigf(go)*tanhf(cn);
        cT[ca] = cn;
        st32cv(&hT[(size_t)nxt*HSLAB + ca], hn);
      }
    }
    gbar_nf(bar, kbar); kbar++;

    // ===== Phase B: xi = h_new @ w_xi. WG=(q,fc): 81 f x 4 b, K-split-4 =====
    {
      const float* hsrc = hT + (size_t)nxt*HSLAB;
      for (int u = tid; u < 1024; u += NT){
        int kg = u >> 3, rem = u & 7, bi = rem >> 1, hf = rem & 1;
        stage64(s_x + kg*16 + bi*4 + hf*2, hsrc + kg*128 + (b0+bi)*4 + hf*2);
      }
      __syncthreads();
      const int ks = tid & 3;
      const int bb = (tid >> 2) & 3;
      const int fi = tid >> 4;              // 0..63
      #pragma unroll
      for (int round = 0; round < 2; ++round){
        int fl = round*64 + fi;
        int f  = ch*81 + fl;
        bool ok = (fl < 81) && (f < IFz);
        int fr = ok ? f : 0;
        float acc = dotL(s_x + ks*512 + bb*4, 16, wxiT + (size_t)fr*Hz + ks*128, 32);
        acc += __shfl_xor(acc, 1, 64);
        acc += __shfl_xor(acc, 2, 64);
        if (ok && ks == 0)
          st32cv(&xiT[(size_t)(b0+bb)*IFz + f], acc + b_xi[f]);
      }
    }
    gbar_nf(bar, kbar); kbar++;

    // ===== Phase C: memops (WGs 0..31) | out(t-1) (WGs 32..255) =====
    if (blockIdx.x < Bz){
      memops(blockIdx.x, t, xiT, Mg, ug, pg, wwg, Lg, wrg, rT);
    } else if (t > 0){
      const int idx = blockIdx.x - Bz;      // 0..223
      const int oq  = idx / 28;             // 0..7
      const int jc  = idx % 28;             // 0..27
      const int ob0 = oq*4;
      const float* hsrc = hT + (size_t)cur*HSLAB;
      const float* rsrc = rT + (size_t)cur*RSLAB;
      for (int u = tid; u < 3072; u += NT){
        if (u < 1024){
          int kg = u >> 3, rem = u & 7, bi = rem >> 1, hf = rem & 1;
          stage64(s_x + kg*16 + bi*4 + hf*2, hsrc + kg*128 + (ob0+bi)*4 + hf*2);
        } else {
          int u2 = u - 1024;
          int kg = u2 >> 3, rem = u2 & 7, bi = rem >> 1, hf = rem & 1;
          stage64(s_x + 2048 + kg*16 + bi*4 + hf*2, rsrc + kg*128 + (ob0+bi)*4 + hf*2);
        }
      }
      __syncthreads();
      const int ks = tid & 3;
      const int bb = (tid >> 2) & 3;
      const int ji = tid >> 4;              // 0..63
      const int j  = jc*19 + ji;
      if (ji < 19 && j < 512){
        const float* wj = woutT + (size_t)j*XD;
        float acc;
        if (ks == 0)      acc = dotL(s_x + bb*4,           16, wj,         128);  // h[0:512]
        else if (ks == 1) acc = dotL(s_x + 2048 + bb*4,    16, wj + 512,    96);  // r[0:384]
        else if (ks == 2) acc = dotL(s_x + 3584 + bb*4,    16, wj + 896,    96);  // r[384:768]
        else              acc = dotL(s_x + 5120 + bb*4,    16, wj + 1280,   64);  // r[768:1024]
        acc += __shfl_xor(acc, 1, 64);
        acc += __shfl_xor(acc, 2, 64);
        if (ks == 0)
          out[(size_t)(ob0+bb)*Tz*Hz + (size_t)(t-1)*Hz + j] = acc + b_out[j];
      }
    }
    gbar_nf(bar, kbar); kbar++;
  }

  gbar_fence(bar, kbar); kbar++;   // make coherent state + private cT readable via cache

  // ---- epilogue (R7-verbatim): out(T-1), final h, c (state in buffer 0) ----
  if (gid < 2*Hz*Bz){
    const int ks = gid & 1;
    const int o  = gid >> 1;
    const int b  = o & 31;
    const int j  = o >> 5;
    const float* wj = woutT + (size_t)j*XD;
    float acc;
    if (ks == 0) acc = dotI(hT + b*4, wj, 128) + dotI(rT + b*4, wj + Hz, 64);
    else         acc = dotI(rT + 64*128 + b*4, wj + Hz + 256, 192);
    acc += __shfl_xor(acc, 1, 64);
    if (ks == 0)
      out[(size_t)b*Tz*Hz + (size_t)(Tz-1)*Hz + j] = acc + b_out[j];
  }
  if (gid < Hz*Bz){
    const int b = gid & 31, j = gid >> 5;
    const int ca = (j>>2)*128 + b*4 + (j&3);
    out[(size_t)Bz*Tz*Hz + (size_t)b*Hz + j]                 = hT[ca];
    out[(size_t)Bz*Tz*Hz + (size_t)Bz*Hz + (size_t)b*Hz + j] = cT[ca];
  }
}

extern "C" void kernel_launch(void* const* d_in, const int* in_sizes, int n_in,
                              void* d_out, int out_size, void* d_ws, size_t ws_size,
                              hipStream_t stream)
{
  const int*   src    = (const int*)  d_in[0];
  // d_in[1] = source_lengths (unused by reference)
  const float* emb    = (const float*)d_in[2];
  const float* w_ih   = (const float*)d_in[3];
  const float* w_hh   = (const float*)d_in[4];
  const float* b_lstm = (const float*)d_in[5];
  const float* w_xi   = (const float*)d_in[6];
  const float* b_xi   = (const float*)d_in[7];
  const float* w_out  = (const float*)d_in[8];
  const float* b_out  = (const float*)d_in[9];
  float* out = (float*)d_out;
  float* ws  = (float*)d_ws;

  hipMemsetAsync((char*)d_ws + (size_t)BAR_OFF*4, 0, 8192, stream);

  void* args[] = { &src, &emb, &w_ih, &w_hh, &b_lstm, &w_xi, &b_xi, &w_out, &b_out, &out, &ws };
  hipLaunchCooperativeKernel((const void*)dnc_kernel, dim3(NWG), dim3(NT), args, 0, stream);
}

// Round 11
// 30703.201 us; speedup vs baseline: 2.2576x; 1.2303x over previous
//
#include <hip/hip_runtime.h>

#define Bz 32
#define Tz 256
#define Hz 512
#define Nz 5
#define Rz 2
#define Wz 512
#define RWz 1024
#define XD 1536          // H + R*W
#define IFz 2573
#define EPSF 1e-6f
#define NWG 256
#define NT 1024
#define NTH (NWG*NT)     // 262144

#define HTB (Bz*Hz)      // 16384 floats per h buffer
#define RTB (Bz*RWz)     // 32768 floats per r buffer

// workspace float offsets (same totals as R7/R9 runs)
#define WXIT_OFF (Tz*Bz*Hz)                            // 4194304
#define WOUT_OFF (WXIT_OFF + IFz*Hz)                   // 5511680
#define HT_OFF   (WOUT_OFF + Hz*XD)                    // 6298112
#define CT_OFF   (HT_OFF + 2*HTB)                      // 6330880
#define RT_OFF   (CT_OFF + HTB)                        // 6347264
#define XIT_OFF  (RT_OFF + 2*RTB)                      // 6412800
#define MG_OFF   (XIT_OFF + IFz*Bz)                    // 6495136
#define UG_OFF   (MG_OFF + Bz*Nz*Wz)                   // 6577056
#define BAR_OFF  (UG_OFF + 1600 + 32)                  // 6578688 (64-aligned)

// xi field offsets
#define O_KR 0
#define O_BR 1024
#define O_KW 1026
#define O_BW 1538
#define O_E  1539
#define O_V  2051
#define O_FG 2563
#define O_GA 2565
#define O_GW 2566
#define O_PI 2567

typedef unsigned long long u64;

__device__ __forceinline__ float sigf(float x){ return 1.0f/(1.0f+expf(-x)); }
__device__ __forceinline__ float splus(float x){ return fmaxf(x,0.0f) + log1pf(expf(-fabsf(x))); }

// coherent accessors (proven R7/R9)
__device__ __forceinline__ void stage64(float* dst_lds, const float* src){
  u64 v = __hip_atomic_load((const u64*)src, __ATOMIC_RELAXED, __HIP_MEMORY_SCOPE_AGENT);
  *(u64*)dst_lds = v;
}
__device__ __forceinline__ float ld32cv(const float* p){
  return __hip_atomic_load(p, __ATOMIC_RELAXED, __HIP_MEMORY_SCOPE_AGENT);
}
__device__ __forceinline__ void st32cv(float* p, float v){
  __hip_atomic_store(p, v, __ATOMIC_RELAXED, __HIP_MEMORY_SCOPE_AGENT);
}

// ---- grid barriers (verbatim from R7/R9 runs) ----
__device__ __forceinline__ void gbar_fence(unsigned* bar, unsigned k){
  __syncthreads();
  const int tid = threadIdx.x;
  const unsigned wg = blockIdx.x;
  if (tid == 0){
    __builtin_amdgcn_fence(__ATOMIC_RELEASE, "agent");
    __hip_atomic_fetch_add(&bar[(wg & 15u)*64], 1u, __ATOMIC_RELAXED, __HIP_MEMORY_SCOPE_AGENT);
  }
  if (wg == 0){
    if (tid < 16){
      const unsigned tgt = (NWG/16u)*(k+1u);
      while (__hip_atomic_load(&bar[tid*64], __ATOMIC_RELAXED, __HIP_MEMORY_SCOPE_AGENT) < tgt)
        __builtin_amdgcn_s_sleep(1);
    }
    __syncthreads();
    if (tid < 16){
      __builtin_amdgcn_fence(__ATOMIC_ACQ_REL, "agent");
      __hip_atomic_store(&bar[1024 + tid*64], k+1u, __ATOMIC_RELAXED, __HIP_MEMORY_SCOPE_AGENT);
    }
    __syncthreads();
  } else {
    if (tid == 0){
      while (__hip_atomic_load(&bar[1024 + (wg & 15u)*64], __ATOMIC_RELAXED, __HIP_MEMORY_SCOPE_AGENT) < k+1u)
        __builtin_amdgcn_s_sleep(1);
      __builtin_amdgcn_fence(__ATOMIC_ACQUIRE, "agent");
    }
    __syncthreads();
  }
}
__device__ __forceinline__ void gbar_nf(unsigned* bar, unsigned k){
  __syncthreads();
  const int tid = threadIdx.x;
  const unsigned wg = blockIdx.x;
  if (tid == 0){
    asm volatile("s_waitcnt vmcnt(0) lgkmcnt(0)" ::: "memory");
    __hip_atomic_fetch_add(&bar[(wg & 15u)*64], 1u, __ATOMIC_RELAXED, __HIP_MEMORY_SCOPE_AGENT);
  }
  if (wg == 0){
    if (tid < 16){
      const unsigned tgt = (NWG/16u)*(k+1u);
      while (__hip_atomic_load(&bar[tid*64], __ATOMIC_RELAXED, __HIP_MEMORY_SCOPE_AGENT) < tgt)
        __builtin_amdgcn_s_sleep(1);
    }
    __syncthreads();
    if (tid < 16)
      __hip_atomic_store(&bar[1024 + tid*64], k+1u, __ATOMIC_RELAXED, __HIP_MEMORY_SCOPE_AGENT);
    __syncthreads();
  } else {
    if (tid == 0){
      while (__hip_atomic_load(&bar[1024 + (wg & 15u)*64], __ATOMIC_RELAXED, __HIP_MEMORY_SCOPE_AGENT) < k+1u)
        __builtin_amdgcn_s_sleep(1);
    }
    __syncthreads();
  }
}

// contiguous · contiguous dot, float4 both sides
__device__ __forceinline__ float dot4c(const float* __restrict__ x,
                                       const float* __restrict__ w, int n){
  const float4* x4 = (const float4*)x;
  const float4* w4 = (const float4*)w;
  float a0=0.f,a1=0.f,a2=0.f,a3=0.f;
  #pragma unroll 8
  for (int i=0;i<n/4;i++){
    float4 xv=x4[i], wv=w4[i];
    a0=fmaf(xv.x,wv.x,a0); a1=fmaf(xv.y,wv.y,a1);
    a2=fmaf(xv.z,wv.z,a2); a3=fmaf(xv.w,wv.w,a3);
  }
  return (a0+a1)+(a2+a3);
}

__device__ void memops(int b, int t, const float* xiT,
                       float* Mg, float* ug, float* pg, float* wwg, float* Lg, float* wrg,
                       float* rT)
{
  __shared__ float s_xi[IFz];
  __shared__ float s_M[Nz*Wz];
  __shared__ float s_u[Nz], s_p[Nz], s_ww[Nz], s_a[Nz], s_L[Nz*Nz], s_wr[Rz*Nz];
  __shared__ float s_sc[13];
  __shared__ float s_m2[Nz], s_dt[Nz], s_d0[Nz], s_d1[Nz];
  __shared__ float s_kw2, s_kr2[2];
  __shared__ float s_fwd[Rz*Nz], s_bwd[Rz*Nz];

  const int tid = threadIdx.x;
  const int wv = tid >> 6, ln = tid & 63;

  for (int f = tid; f < IFz; f += NT) s_xi[f] = ld32cv(&xiT[(size_t)b*IFz + f]);
  for (int i = tid; i < Nz*Wz; i += NT) s_M[i] = Mg[(size_t)b*Nz*Wz + i];
  if (tid < Nz){ s_u[tid]=ug[b*Nz+tid]; s_p[tid]=pg[b*Nz+tid]; s_ww[tid]=wwg[b*Nz+tid]; }
  if (tid < Nz*Nz) s_L[tid] = Lg[b*Nz*Nz+tid];
  if (tid < Rz*Nz) s_wr[tid] = wrg[b*Rz*Nz+tid];
  __syncthreads();

  if (tid == 0){
    s_sc[0] = 1.0f + splus(s_xi[O_BR+0]);
    s_sc[1] = 1.0f + splus(s_xi[O_BR+1]);
    s_sc[2] = 1.0f + splus(s_xi[O_BW]);
    s_sc[3] = sigf(s_xi[O_FG+0]);
    s_sc[4] = sigf(s_xi[O_FG+1]);
    s_sc[5] = sigf(s_xi[O_GA]);
    s_sc[6] = sigf(s_xi[O_GW]);
    for (int r=0;r<Rz;r++){
      float x0=s_xi[O_PI+r*3+0], x1=s_xi[O_PI+r*3+1], x2=s_xi[O_PI+r*3+2];
      float m = fmaxf(x0,fmaxf(x1,x2));
      float e0=expf(x0-m), e1=expf(x1-m), e2=expf(x2-m);
      float s = e0+e1+e2;
      s_sc[7+r*3+0]=e0/s; s_sc[7+r*3+1]=e1/s; s_sc[7+r*3+2]=e2/s;
    }
  }
  __syncthreads();

  if (tid < Nz){
    float psi = (1.0f - s_sc[3]*s_wr[0*Nz+tid]) * (1.0f - s_sc[4]*s_wr[1*Nz+tid]);
    float uu = s_u[tid], w = s_ww[tid];
    s_u[tid] = (uu + w - uu*w) * psi;
  }

  // cosine(M_old, kw)
  if (wv < 4){
    const int n = wv;
    float pd=0.f, pm=0.f;
    for (int w = ln; w < Wz; w += 64){
      float kv = s_xi[O_KW+w], mv = s_M[n*Wz+w];
      pd = fmaf(kv,mv,pd); pm = fmaf(mv,mv,pm);
    }
    for (int off=32; off; off>>=1){ pd += __shfl_down(pd,off,64); pm += __shfl_down(pm,off,64); }
    if (ln==0){ s_dt[n]=pd; s_m2[n]=pm; }
  }
  if (wv == 3){
    float p2=0.f;
    for (int w=ln; w<Wz; w+=64){ float kv=s_xi[O_KW+w]; p2=fmaf(kv,kv,p2); }
    for (int off=32; off; off>>=1) p2 += __shfl_down(p2,off,64);
    if (ln==0) s_kw2 = p2;
  }
  __syncthreads();
  if (wv == 0){
    const int n = 4;
    float pd=0.f, pm=0.f;
    for (int w = ln; w < Wz; w += 64){
      float kv = s_xi[O_KW+w], mv = s_M[n*Wz+w];
      pd = fmaf(kv,mv,pd); pm = fmaf(mv,mv,pm);
    }
    for (int off=32; off; off>>=1){ pd += __shfl_down(pd,off,64); pm += __shfl_down(pm,off,64); }
    if (ln==0){ s_dt[n]=pd; s_m2[n]=pm; }
  }
  __syncthreads();

  if (tid == 0){
    float su[Nz]; int idx[Nz];
    for (int i=0;i<Nz;i++){
      float v = EPSF + (1.0f-EPSF)*s_u[i];
      int j=i;
      while (j>0 && su[j-1] > v){ su[j]=su[j-1]; idx[j]=idx[j-1]; j--; }
      su[j]=v; idx[j]=i;
    }
    float cp = 1.0f;
    for (int k=0;k<Nz;k++){ s_a[idx[k]] = (1.0f - su[k])*cp; cp *= su[k]; }
    float rk = rsqrtf(s_kw2 + EPSF);
    float lg[Nz], mx=-1e30f;
    for (int n=0;n<Nz;n++){ lg[n] = s_sc[2]*s_dt[n]*rk*rsqrtf(s_m2[n]+EPSF); mx=fmaxf(mx,lg[n]); }
    float ssum=0.f;
    for (int n=0;n<Nz;n++){ lg[n]=expf(lg[n]-mx); ssum+=lg[n]; }
    float ga=s_sc[5], gw=s_sc[6];
    for (int n=0;n<Nz;n++){ float cwn = lg[n]/ssum; s_ww[n] = gw*(ga*s_a[n] + (1.0f-ga)*cwn); }
  }
  __syncthreads();

  for (int i = tid; i < Nz*Wz; i += NT){
    int n = i >> 9, w = i & 511;
    float e = sigf(s_xi[O_E+w]);
    float v = s_xi[O_V+w];
    s_M[i] = s_M[i]*(1.0f - s_ww[n]*e) + s_ww[n]*v;
  }
  __syncthreads();

  if (tid == 0){
    float wsum = 0.f;
    for (int n=0;n<Nz;n++) wsum += s_ww[n];
    float Lo[Nz*Nz];
    for (int i=0;i<Nz;i++)
      for (int j=0;j<Nz;j++)
        Lo[i*Nz+j] = (i==j) ? 0.0f : ((1.0f - s_ww[i] - s_ww[j])*s_L[i*Nz+j] + s_ww[i]*s_p[j]);
    for (int i=0;i<Nz*Nz;i++) s_L[i]=Lo[i];
    for (int j=0;j<Nz;j++) s_p[j] = (1.0f-wsum)*s_p[j] + s_ww[j];
    for (int r=0;r<Rz;r++)
      for (int n=0;n<Nz;n++){
        float f=0.f, bb=0.f;
        for (int m=0;m<Nz;m++){ f = fmaf(s_L[n*Nz+m], s_wr[r*Nz+m], f); bb = fmaf(s_L[m*Nz+n], s_wr[r*Nz+m], bb); }
        s_fwd[r*Nz+n]=f; s_bwd[r*Nz+n]=bb;
      }
  }
  __syncthreads();

  // cosine(M_new, kr)
  if (wv < 4){
    const int n = wv;
    float pm=0.f,p0=0.f,p1=0.f;
    for (int w=ln; w<Wz; w+=64){
      float mv=s_M[n*Wz+w];
      pm=fmaf(mv,mv,pm);
      p0=fmaf(s_xi[O_KR+w],    mv,p0);
      p1=fmaf(s_xi[O_KR+Wz+w], mv,p1);
    }
    for (int off=32; off; off>>=1){
      pm += __shfl_down(pm,off,64); p0 += __shfl_down(p0,off,64); p1 += __shfl_down(p1,off,64);
    }
    if (ln==0){ s_m2[n]=pm; s_d0[n]=p0; s_d1[n]=p1; }
  }
  __syncthreads();
  if (wv == 0){
    const int n = 4;
    float pm=0.f,p0=0.f,p1=0.f;
    for (int w=ln; w<Wz; w+=64){
      float mv=s_M[n*Wz+w];
      pm=fmaf(mv,mv,pm);
      p0=fmaf(s_xi[O_KR+w],    mv,p0);
      p1=fmaf(s_xi[O_KR+Wz+w], mv,p1);
    }
    for (int off=32; off; off>>=1){
      pm += __shfl_down(pm,off,64); p0 += __shfl_down(p0,off,64); p1 += __shfl_down(p1,off,64);
    }
    if (ln==0){ s_m2[n]=pm; s_d0[n]=p0; s_d1[n]=p1; }
  } else if (wv == 1 || wv == 2){
    const int r = wv - 1;
    float p2=0.f;
    for (int w=ln; w<Wz; w+=64){ float kv=s_xi[O_KR+r*Wz+w]; p2=fmaf(kv,kv,p2); }
    for (int off=32; off; off>>=1) p2 += __shfl_down(p2,off,64);
    if (ln==0) s_kr2[r]=p2;
  }
  __syncthreads();

  if (tid == 0){
    for (int r=0;r<Rz;r++){
      float rk = rsqrtf(s_kr2[r]+EPSF);
      const float* dd = (r==0) ? s_d0 : s_d1;
      float br = s_sc[r];
      float lg[Nz], mx=-1e30f;
      for (int n=0;n<Nz;n++){ lg[n] = br*dd[n]*rk*rsqrtf(s_m2[n]+EPSF); mx=fmaxf(mx,lg[n]); }
      float ssum=0.f;
      for (int n=0;n<Nz;n++){ lg[n]=expf(lg[n]-mx); ssum+=lg[n]; }
      for (int n=0;n<Nz;n++){
        float crn = lg[n]/ssum;
        s_wr[r*Nz+n] = s_sc[7+r*3+0]*s_bwd[r*Nz+n] + s_sc[7+r*3+1]*crn + s_sc[7+r*3+2]*s_fwd[r*Nz+n];
      }
    }
  }
  __syncthreads();

  // read vectors -> rT[nxt][b][r*512+w] (coherent, contiguous) + private state (cached)
  float* rdst = rT + (size_t)((t+1)&1)*RTB + (size_t)b*RWz;
  for (int w = tid; w < Wz; w += NT){
    float m0=s_M[0*Wz+w], m1=s_M[1*Wz+w], m2=s_M[2*Wz+w], m3=s_M[3*Wz+w], m4=s_M[4*Wz+w];
    #pragma unroll
    for (int r=0;r<Rz;r++){
      float rv = s_wr[r*Nz+0]*m0 + s_wr[r*Nz+1]*m1 + s_wr[r*Nz+2]*m2
               + s_wr[r*Nz+3]*m3 + s_wr[r*Nz+4]*m4;
      st32cv(&rdst[r*Wz + w], rv);
    }
  }
  for (int i = tid; i < Nz*Wz; i += NT) Mg[(size_t)b*Nz*Wz+i] = s_M[i];
  if (tid < Nz){ ug[b*Nz+tid]=s_u[tid]; pg[b*Nz+tid]=s_p[tid]; wwg[b*Nz+tid]=s_ww[tid]; }
  if (tid < Nz*Nz) Lg[b*Nz*Nz+tid]=s_L[tid];
  if (tid < Rz*Nz) wrg[b*Rz*Nz+tid]=s_wr[tid];
}

__global__ void __launch_bounds__(NT, 4)
dnc_kernel(const int* __restrict__ src, const float* __restrict__ emb,
           const float* __restrict__ w_ih, const float* __restrict__ w_hh,
           const float* __restrict__ b_lstm,
           const float* __restrict__ w_xi, const float* __restrict__ b_xi,
           const float* __restrict__ w_out, const float* __restrict__ b_out,
           float* __restrict__ out, float* __restrict__ ws)
{
  __shared__ __align__(16) float s_x[2048];   // 8 KB: [h 512 | r 1024 | emb 512]

  const int tid = threadIdx.x;
  const int gid = blockIdx.x*NT + tid;

  float* embT  = ws;                       // [T][B][512]   cached RO
  float* wxiT  = ws + WXIT_OFF;            // [IF][512]     cached RO
  float* woutT = ws + WOUT_OFF;            // [512][1536]   cached RO ([h|r] cols)
  float* hT    = ws + HT_OFF;              // [2][B][512]   coherent
  float* cT    = ws + CT_OFF;              // [B][512]      cached, WG-pinned
  float* rT    = ws + RT_OFF;              // [2][B][1024]  coherent
  float* xiT   = ws + XIT_OFF;             // [B][IFz]      coherent
  float* Mg    = ws + MG_OFF;              // [B][2560]     cached, WG-pinned
  float* ug    = ws + UG_OFF;
  float* pg    = ug + Bz*Nz;
  float* wwg   = pg + Bz*Nz;
  float* Lg    = wwg + Bz*Nz;
  float* wrg   = Lg + Bz*Nz*Nz;
  unsigned* bar = (unsigned*)(ws + BAR_OFF);
  unsigned kbar = 0;

  // ---- init ----
  {
    float4* embT4 = (float4*)embT;
    const float4* emb4 = (const float4*)emb;
    for (int i = gid; i < Tz*Bz*128; i += NTH){   // i = t*4096 + b*128 + kg
      int kg = i & 127, b = (i>>7) & 31, tt = i >> 12;
      embT4[i] = emb4[(size_t)src[b*Tz+tt]*128 + kg];
    }
  }
  for (size_t i = gid; i < (size_t)IFz*Hz; i += NTH){
    int k = (int)(i % Hz); size_t f = i / Hz;
    wxiT[i] = w_xi[(size_t)k*IFz + f];
  }
  for (size_t i = gid; i < (size_t)Hz*XD; i += NTH){
    int k = (int)(i % XD); int j = (int)(i / XD);
    woutT[i] = w_out[(size_t)k*Hz + j];
  }
  for (int i = gid; i < 2*HTB; i += NTH) hT[i]=0.f;
  for (int i = gid; i < HTB;   i += NTH) cT[i]=0.f;
  for (int i = gid; i < 2*RTB; i += NTH) rT[i]=0.f;
  for (int i = gid; i < Bz*Nz*Wz;i += NTH) Mg[i]=0.f;
  for (int i = gid; i < Bz*(3*Nz + Nz*Nz + Rz*Nz); i += NTH) ug[i]=0.f;
  gbar_fence(bar, kbar); kbar++;

  const int b  = blockIdx.x >> 3;   // 0..31  batch
  const int jc = blockIdx.x & 7;    // 0..7   row-chunk  (== XCD id -> weight pinning)

  // ---- time loop (no agent fences inside) ----
  for (int t = 0; t < Tz; ++t){
    const int cur = t & 1, nxt = (t+1)&1;

    // ===== Phase A: gates GEMV (64 j x 4 gates, K-split-4) + fused out(t-1) =====
    {
      const float* hsrc = hT + (size_t)cur*HTB + (size_t)b*Hz;
      const float* rsrc = rT + (size_t)cur*RTB + (size_t)b*RWz;
      const float* esrc = embT + ((size_t)t*Bz + b)*Hz;
      if (tid < 256)       stage64(s_x + tid*2, hsrc + tid*2);            // s_x[0:512] = h
      else if (tid < 768)  stage64(s_x + tid*2, rsrc + (tid-256)*2);      // s_x[512:1536] = r
      else if (tid < 896){ int u = tid - 768;                             // s_x[1536:2048] = emb
        *(float4*)(s_x + 1536 + u*4) = *(const float4*)(esrc + u*4);
      }
      __syncthreads();

      // gates: tid = jj(6b) | gate(2b) | ks(2b)
      {
        const int ks   = tid & 3;
        const int gate = (tid >> 2) & 3;
        const int jj   = tid >> 4;         // 0..63
        const int j    = jc*64 + jj;
        const int row  = gate*Hz + j;
        const float* wp = (ks == 3) ? (w_hh + (size_t)row*Hz)
                                    : (w_ih + (size_t)row*XD + ks*512);
        const float* xb = s_x + ((ks == 0) ? 1536 : (ks == 3) ? 0 : ks*512);
        float acc = dot4c(xb, wp, 512);
        acc += __shfl_xor(acc, 1, 64);
        acc += __shfl_xor(acc, 2, 64);
        acc += b_lstm[row];
        const int lane = tid & 63;
        const int base = lane & ~12;       // zero gate bits
        float gi = __shfl(acc, base+0,  64);
        float gf = __shfl(acc, base+4,  64);
        float gg = __shfl(acc, base+8,  64);
        float go = __shfl(acc, base+12, 64);
        if ((lane & 15) == 0){             // ks==0 && gate==0
          float cv = cT[(size_t)b*Hz + j];
          float cn = sigf(gf)*cv + sigf(gi)*tanhf(gg);
          float hn = sigf(go)*tanhf(cn);
          cT[(size_t)b*Hz + j] = cn;
          st32cv(&hT[(size_t)nxt*HTB + (size_t)b*Hz + j], hn);
        }
      }

      // fused out(t-1): s_x[0:1536] = [h|r] matches woutT row order. 16-way K-split.
      if (t > 0){
        const int oks = tid & 15;          // 0..15, 96 floats each
        const int ojj = tid >> 4;          // 0..63
        const int oj  = jc*64 + ojj;
        float oa = dot4c(s_x + oks*96, woutT + (size_t)oj*XD + oks*96, 96);
        oa += __shfl_xor(oa, 1, 64);
        oa += __shfl_xor(oa, 2, 64);
        oa += __shfl_xor(oa, 4, 64);
        oa += __shfl_xor(oa, 8, 64);
        if (oks == 0)
          out[(size_t)b*Tz*Hz + (size_t)(t-1)*Hz + oj] = oa + b_out[oj];
      }
    }
    gbar_nf(bar, kbar); kbar++;

    // ===== Phase B: xi = h_new @ w_xi (f-chunk fc=jc, K-split-4) =====
    {
      if (tid < 256) stage64(s_x + tid*2, hT + (size_t)nxt*HTB + (size_t)b*Hz + tid*2);
      __syncthreads();
      const int ks  = tid & 3;
      const int fi0 = tid >> 2;            // 0..255
      #pragma unroll
      for (int round = 0; round < 2; ++round){
        int fi = round*256 + fi0;
        int f  = jc*322 + fi;
        bool ok = (fi < 322) && (f < IFz);
        int fr = ok ? f : 0;
        float acc = dot4c(s_x + ks*128, wxiT + (size_t)fr*Hz + ks*128, 128);
        acc += __shfl_xor(acc, 1, 64);
        acc += __shfl_xor(acc, 2, 64);
        if (ok && ks == 0)
          st32cv(&xiT[(size_t)b*IFz + f], acc + b_xi[f]);
      }
    }
    gbar_nf(bar, kbar); kbar++;

    // ===== Phase C: memops only (1 WG per batch, spread over XCDs) =====
    if (jc == (b & 7)){
      memops(b, t, xiT, Mg, ug, pg, wwg, Lg, wrg, rT);
    }
    gbar_nf(bar, kbar); kbar++;
  }

  gbar_fence(bar, kbar); kbar++;   // make coherent state + private cT cache-readable

  // ---- epilogue: out(T-1), final h, c (state in buffer 0) ----
  if (gid < Bz*Hz){
    const int eb = gid >> 9, ej = gid & 511;
    const float* wj = woutT + (size_t)ej*XD;
    float acc = dot4c(hT + (size_t)eb*Hz,  wj,       512)
              + dot4c(rT + (size_t)eb*RWz, wj + 512, 1024)
              + b_out[ej];
    out[(size_t)eb*Tz*Hz + (size_t)(Tz-1)*Hz + ej] = acc;
    out[(size_t)Bz*Tz*Hz + (size_t)eb*Hz + ej]       = hT[(size_t)eb*Hz + ej];
    out[(size_t)Bz*Tz*Hz + HTB + (size_t)eb*Hz + ej] = cT[(size_t)eb*Hz + ej];
  }
}

extern "C" void kernel_launch(void* const* d_in, const int* in_sizes, int n_in,
                              void* d_out, int out_size, void* d_ws, size_t ws_size,
                              hipStream_t stream)
{
  const int*   src    = (const int*)  d_in[0];
  // d_in[1] = source_lengths (unused by reference)
  const float* emb    = (const float*)d_in[2];
  const float* w_ih   = (const float*)d_in[3];
  const float* w_hh   = (const float*)d_in[4];
  const float* b_lstm = (const float*)d_in[5];
  const float* w_xi   = (const float*)d_in[6];
  const float* b_xi   = (const float*)d_in[7];
  const float* w_out  = (const float*)d_in[8];
  const float* b_out  = (const float*)d_in[9];
  float* out = (float*)d_out;
  float* ws  = (float*)d_ws;

  hipMemsetAsync((char*)d_ws + (size_t)BAR_OFF*4, 0, 8192, stream);

  void* args[] = { &src, &emb, &w_ih, &w_hh, &b_lstm, &w_xi, &b_xi, &w_out, &b_out, &out, &ws };
  hipLaunchCooperativeKernel((const void*)dnc_kernel, dim3(NWG), dim3(NT), args, 0, stream);
}

// Round 12
// 20289.638 us; speedup vs baseline: 3.4163x; 1.5132x over previous
//
#include <hip/hip_runtime.h>

#define Bz 32
#define Tz 256
#define Hz 512
#define Nz 5
#define Rz 2
#define Wz 512
#define RWz 1024
#define XD 1536          // H + R*W
#define IFz 2573
#define EPSF 1e-6f
#define NWG 256
#define NT 1024
#define NTH (NWG*NT)     // 262144

#define HTB (Bz*Hz)      // 16384 floats per h buffer
#define RTB (Bz*RWz)     // 32768 floats per r buffer

// workspace float offsets (same as R10 run)
#define WXIT_OFF (Tz*Bz*Hz)                            // 4194304
#define WOUT_OFF (WXIT_OFF + IFz*Hz)                   // 5511680
#define HT_OFF   (WOUT_OFF + Hz*XD)                    // 6298112
#define CT_OFF   (HT_OFF + 2*HTB)                      // 6330880
#define RT_OFF   (CT_OFF + HTB)                        // 6347264
#define XIT_OFF  (RT_OFF + 2*RTB)                      // 6412800
#define MG_OFF   (XIT_OFF + IFz*Bz)                    // 6495136
#define UG_OFF   (MG_OFF + Bz*Nz*Wz)                   // 6577056
#define BAR_OFF  (UG_OFF + 1600 + 32)                  // 6578688 (64-aligned)

// xi field offsets
#define O_KR 0
#define O_BR 1024
#define O_KW 1026
#define O_BW 1538
#define O_E  1539
#define O_V  2051
#define O_FG 2563
#define O_GA 2565
#define O_GW 2566
#define O_PI 2567

typedef unsigned long long u64;

__device__ __forceinline__ float sigf(float x){ return 1.0f/(1.0f+expf(-x)); }
__device__ __forceinline__ float splus(float x){ return fmaxf(x,0.0f) + log1pf(expf(-fabsf(x))); }

// coherent accessors (proven R7/R9/R10)
__device__ __forceinline__ void stage64(float* dst_lds, const float* src){
  u64 v = __hip_atomic_load((const u64*)src, __ATOMIC_RELAXED, __HIP_MEMORY_SCOPE_AGENT);
  *(u64*)dst_lds = v;
}
__device__ __forceinline__ float ld32cv(const float* p){
  return __hip_atomic_load(p, __ATOMIC_RELAXED, __HIP_MEMORY_SCOPE_AGENT);
}
__device__ __forceinline__ void st32cv(float* p, float v){
  __hip_atomic_store(p, v, __ATOMIC_RELAXED, __HIP_MEMORY_SCOPE_AGENT);
}

// ---- grid barriers (verbatim from R10 run) ----
__device__ __forceinline__ void gbar_fence(unsigned* bar, unsigned k){
  __syncthreads();
  const int tid = threadIdx.x;
  const unsigned wg = blockIdx.x;
  if (tid == 0){
    __builtin_amdgcn_fence(__ATOMIC_RELEASE, "agent");
    __hip_atomic_fetch_add(&bar[(wg & 15u)*64], 1u, __ATOMIC_RELAXED, __HIP_MEMORY_SCOPE_AGENT);
  }
  if (wg == 0){
    if (tid < 16){
      const unsigned tgt = (NWG/16u)*(k+1u);
      while (__hip_atomic_load(&bar[tid*64], __ATOMIC_RELAXED, __HIP_MEMORY_SCOPE_AGENT) < tgt)
        __builtin_amdgcn_s_sleep(1);
    }
    __syncthreads();
    if (tid < 16){
      __builtin_amdgcn_fence(__ATOMIC_ACQ_REL, "agent");
      __hip_atomic_store(&bar[1024 + tid*64], k+1u, __ATOMIC_RELAXED, __HIP_MEMORY_SCOPE_AGENT);
    }
    __syncthreads();
  } else {
    if (tid == 0){
      while (__hip_atomic_load(&bar[1024 + (wg & 15u)*64], __ATOMIC_RELAXED, __HIP_MEMORY_SCOPE_AGENT) < k+1u)
        __builtin_amdgcn_s_sleep(1);
      __builtin_amdgcn_fence(__ATOMIC_ACQUIRE, "agent");
    }
    __syncthreads();
  }
}
__device__ __forceinline__ void gbar_nf(unsigned* bar, unsigned k){
  __syncthreads();
  const int tid = threadIdx.x;
  const unsigned wg = blockIdx.x;
  if (tid == 0){
    asm volatile("s_waitcnt vmcnt(0) lgkmcnt(0)" ::: "memory");
    __hip_atomic_fetch_add(&bar[(wg & 15u)*64], 1u, __ATOMIC_RELAXED, __HIP_MEMORY_SCOPE_AGENT);
  }
  if (wg == 0){
    if (tid < 16){
      const unsigned tgt = (NWG/16u)*(k+1u);
      while (__hip_atomic_load(&bar[tid*64], __ATOMIC_RELAXED, __HIP_MEMORY_SCOPE_AGENT) < tgt)
        __builtin_amdgcn_s_sleep(1);
    }
    __syncthreads();
    if (tid < 16)
      __hip_atomic_store(&bar[1024 + tid*64], k+1u, __ATOMIC_RELAXED, __HIP_MEMORY_SCOPE_AGENT);
    __syncthreads();
  } else {
    if (tid == 0){
      while (__hip_atomic_load(&bar[1024 + (wg & 15u)*64], __ATOMIC_RELAXED, __HIP_MEMORY_SCOPE_AGENT) < k+1u)
        __builtin_amdgcn_s_sleep(1);
    }
    __syncthreads();
  }
}

// contiguous · contiguous dot (epilogue)
__device__ __forceinline__ float dot4c(const float* __restrict__ x,
                                       const float* __restrict__ w, int n){
  const float4* x4 = (const float4*)x;
  const float4* w4 = (const float4*)w;
  float a0=0.f,a1=0.f,a2=0.f,a3=0.f;
  #pragma unroll 8
  for (int i=0;i<n/4;i++){
    float4 xv=x4[i], wv=w4[i];
    a0=fmaf(xv.x,wv.x,a0); a1=fmaf(xv.y,wv.y,a1);
    a2=fmaf(xv.z,wv.z,a2); a3=fmaf(xv.w,wv.w,a3);
  }
  return (a0+a1)+(a2+a3);
}
// strided dot: float4 at stride `strf` floats (x and w pre-offset by lane slice)
__device__ __forceinline__ float dotS(const float* x, const float* __restrict__ w,
                                      int iters, int strf){
  float a0=0.f,a1=0.f,a2=0.f,a3=0.f;
  #pragma unroll 8
  for (int i=0;i<iters;i++){
    float4 xv = *(const float4*)(x + (size_t)i*strf);
    float4 wv = *(const float4*)(w + (size_t)i*strf);
    a0=fmaf(xv.x,wv.x,a0); a1=fmaf(xv.y,wv.y,a1);
    a2=fmaf(xv.z,wv.z,a2); a3=fmaf(xv.w,wv.w,a3);
  }
  return (a0+a1)+(a2+a3);
}

__device__ void memops(int b, int t, const float* xiT,
                       float* Mg, float* ug, float* pg, float* wwg, float* Lg, float* wrg,
                       float* rT)
{
  __shared__ float s_xi[IFz];
  __shared__ float s_M[Nz*Wz];
  __shared__ float s_u[Nz], s_p[Nz], s_ww[Nz], s_a[Nz], s_L[Nz*Nz], s_wr[Rz*Nz];
  __shared__ float s_sc[13];
  __shared__ float s_m2[Nz], s_dt[Nz], s_d0[Nz], s_d1[Nz];
  __shared__ float s_kw2, s_kr2[2];
  __shared__ float s_fwd[Rz*Nz], s_bwd[Rz*Nz];

  const int tid = threadIdx.x;
  const int wv = tid >> 6, ln = tid & 63;

  for (int f = tid; f < IFz; f += NT) s_xi[f] = ld32cv(&xiT[(size_t)b*IFz + f]);
  for (int i = tid; i < Nz*Wz; i += NT) s_M[i] = Mg[(size_t)b*Nz*Wz + i];
  if (tid < Nz){ s_u[tid]=ug[b*Nz+tid]; s_p[tid]=pg[b*Nz+tid]; s_ww[tid]=wwg[b*Nz+tid]; }
  if (tid < Nz*Nz) s_L[tid] = Lg[b*Nz*Nz+tid];
  if (tid < Rz*Nz) s_wr[tid] = wrg[b*Rz*Nz+tid];
  __syncthreads();

  if (tid == 0){
    s_sc[0] = 1.0f + splus(s_xi[O_BR+0]);
    s_sc[1] = 1.0f + splus(s_xi[O_BR+1]);
    s_sc[2] = 1.0f + splus(s_xi[O_BW]);
    s_sc[3] = sigf(s_xi[O_FG+0]);
    s_sc[4] = sigf(s_xi[O_FG+1]);
    s_sc[5] = sigf(s_xi[O_GA]);
    s_sc[6] = sigf(s_xi[O_GW]);
    for (int r=0;r<Rz;r++){
      float x0=s_xi[O_PI+r*3+0], x1=s_xi[O_PI+r*3+1], x2=s_xi[O_PI+r*3+2];
      float m = fmaxf(x0,fmaxf(x1,x2));
      float e0=expf(x0-m), e1=expf(x1-m), e2=expf(x2-m);
      float s = e0+e1+e2;
      s_sc[7+r*3+0]=e0/s; s_sc[7+r*3+1]=e1/s; s_sc[7+r*3+2]=e2/s;
    }
  }
  __syncthreads();

  if (tid < Nz){
    float psi = (1.0f - s_sc[3]*s_wr[0*Nz+tid]) * (1.0f - s_sc[4]*s_wr[1*Nz+tid]);
    float uu = s_u[tid], w = s_ww[tid];
    s_u[tid] = (uu + w - uu*w) * psi;
  }

  // cosine(M_old, kw)
  if (wv < 4){
    const int n = wv;
    float pd=0.f, pm=0.f;
    for (int w = ln; w < Wz; w += 64){
      float kv = s_xi[O_KW+w], mv = s_M[n*Wz+w];
      pd = fmaf(kv,mv,pd); pm = fmaf(mv,mv,pm);
    }
    for (int off=32; off; off>>=1){ pd += __shfl_down(pd,off,64); pm += __shfl_down(pm,off,64); }
    if (ln==0){ s_dt[n]=pd; s_m2[n]=pm; }
  }
  if (wv == 3){
    float p2=0.f;
    for (int w=ln; w<Wz; w+=64){ float kv=s_xi[O_KW+w]; p2=fmaf(kv,kv,p2); }
    for (int off=32; off; off>>=1) p2 += __shfl_down(p2,off,64);
    if (ln==0) s_kw2 = p2;
  }
  __syncthreads();
  if (wv == 0){
    const int n = 4;
    float pd=0.f, pm=0.f;
    for (int w = ln; w < Wz; w += 64){
      float kv = s_xi[O_KW+w], mv = s_M[n*Wz+w];
      pd = fmaf(kv,mv,pd); pm = fmaf(mv,mv,pm);
    }
    for (int off=32; off; off>>=1){ pd += __shfl_down(pd,off,64); pm += __shfl_down(pm,off,64); }
    if (ln==0){ s_dt[n]=pd; s_m2[n]=pm; }
  }
  __syncthreads();

  if (tid == 0){
    float su[Nz]; int idx[Nz];
    for (int i=0;i<Nz;i++){
      float v = EPSF + (1.0f-EPSF)*s_u[i];
      int j=i;
      while (j>0 && su[j-1] > v){ su[j]=su[j-1]; idx[j]=idx[j-1]; j--; }
      su[j]=v; idx[j]=i;
    }
    float cp = 1.0f;
    for (int k=0;k<Nz;k++){ s_a[idx[k]] = (1.0f - su[k])*cp; cp *= su[k]; }
    float rk = rsqrtf(s_kw2 + EPSF);
    float lg[Nz], mx=-1e30f;
    for (int n=0;n<Nz;n++){ lg[n] = s_sc[2]*s_dt[n]*rk*rsqrtf(s_m2[n]+EPSF); mx=fmaxf(mx,lg[n]); }
    float ssum=0.f;
    for (int n=0;n<Nz;n++){ lg[n]=expf(lg[n]-mx); ssum+=lg[n]; }
    float ga=s_sc[5], gw=s_sc[6];
    for (int n=0;n<Nz;n++){ float cwn = lg[n]/ssum; s_ww[n] = gw*(ga*s_a[n] + (1.0f-ga)*cwn); }
  }
  __syncthreads();

  for (int i = tid; i < Nz*Wz; i += NT){
    int n = i >> 9, w = i & 511;
    float e = sigf(s_xi[O_E+w]);
    float v = s_xi[O_V+w];
    s_M[i] = s_M[i]*(1.0f - s_ww[n]*e) + s_ww[n]*v;
  }
  __syncthreads();

  if (tid == 0){
    float wsum = 0.f;
    for (int n=0;n<Nz;n++) wsum += s_ww[n];
    float Lo[Nz*Nz];
    for (int i=0;i<Nz;i++)
      for (int j=0;j<Nz;j++)
        Lo[i*Nz+j] = (i==j) ? 0.0f : ((1.0f - s_ww[i] - s_ww[j])*s_L[i*Nz+j] + s_ww[i]*s_p[j]);
    for (int i=0;i<Nz*Nz;i++) s_L[i]=Lo[i];
    for (int j=0;j<Nz;j++) s_p[j] = (1.0f-wsum)*s_p[j] + s_ww[j];
    for (int r=0;r<Rz;r++)
      for (int n=0;n<Nz;n++){
        float f=0.f, bb=0.f;
        for (int m=0;m<Nz;m++){ f = fmaf(s_L[n*Nz+m], s_wr[r*Nz+m], f); bb = fmaf(s_L[m*Nz+n], s_wr[r*Nz+m], bb); }
        s_fwd[r*Nz+n]=f; s_bwd[r*Nz+n]=bb;
      }
  }
  __syncthreads();

  // cosine(M_new, kr)
  if (wv < 4){
    const int n = wv;
    float pm=0.f,p0=0.f,p1=0.f;
    for (int w=ln; w<Wz; w+=64){
      float mv=s_M[n*Wz+w];
      pm=fmaf(mv,mv,pm);
      p0=fmaf(s_xi[O_KR+w],    mv,p0);
      p1=fmaf(s_xi[O_KR+Wz+w], mv,p1);
    }
    for (int off=32; off; off>>=1){
      pm += __shfl_down(pm,off,64); p0 += __shfl_down(p0,off,64); p1 += __shfl_down(p1,off,64);
    }
    if (ln==0){ s_m2[n]=pm; s_d0[n]=p0; s_d1[n]=p1; }
  }
  __syncthreads();
  if (wv == 0){
    const int n = 4;
    float pm=0.f,p0=0.f,p1=0.f;
    for (int w=ln; w<Wz; w+=64){
      float mv=s_M[n*Wz+w];
      pm=fmaf(mv,mv,pm);
      p0=fmaf(s_xi[O_KR+w],    mv,p0);
      p1=fmaf(s_xi[O_KR+Wz+w], mv,p1);
    }
    for (int off=32; off; off>>=1){
      pm += __shfl_down(pm,off,64); p0 += __shfl_down(p0,off,64); p1 += __shfl_down(p1,off,64);
    }
    if (ln==0){ s_m2[n]=pm; s_d0[n]=p0; s_d1[n]=p1; }
  } else if (wv == 1 || wv == 2){
    const int r = wv - 1;
    float p2=0.f;
    for (int w=ln; w<Wz; w+=64){ float kv=s_xi[O_KR+r*Wz+w]; p2=fmaf(kv,kv,p2); }
    for (int off=32; off; off>>=1) p2 += __shfl_down(p2,off,64);
    if (ln==0) s_kr2[r]=p2;
  }
  __syncthreads();

  if (tid == 0){
    for (int r=0;r<Rz;r++){
      float rk = rsqrtf(s_kr2[r]+EPSF);
      const float* dd = (r==0) ? s_d0 : s_d1;
      float br = s_sc[r];
      float lg[Nz], mx=-1e30f;
      for (int n=0;n<Nz;n++){ lg[n] = br*dd[n]*rk*rsqrtf(s_m2[n]+EPSF); mx=fmaxf(mx,lg[n]); }
      float ssum=0.f;
      for (int n=0;n<Nz;n++){ lg[n]=expf(lg[n]-mx); ssum+=lg[n]; }
      for (int n=0;n<Nz;n++){
        float crn = lg[n]/ssum;
        s_wr[r*Nz+n] = s_sc[7+r*3+0]*s_bwd[r*Nz+n] + s_sc[7+r*3+1]*crn + s_sc[7+r*3+2]*s_fwd[r*Nz+n];
      }
    }
  }
  __syncthreads();

  // read vectors -> rT[nxt][b][r*512+w] (coherent) + private state (cached)
  float* rdst = rT + (size_t)((t+1)&1)*RTB + (size_t)b*RWz;
  for (int w = tid; w < Wz; w += NT){
    float m0=s_M[0*Wz+w], m1=s_M[1*Wz+w], m2=s_M[2*Wz+w], m3=s_M[3*Wz+w], m4=s_M[4*Wz+w];
    #pragma unroll
    for (int r=0;r<Rz;r++){
      float rv = s_wr[r*Nz+0]*m0 + s_wr[r*Nz+1]*m1 + s_wr[r*Nz+2]*m2
               + s_wr[r*Nz+3]*m3 + s_wr[r*Nz+4]*m4;
      st32cv(&rdst[r*Wz + w], rv);
    }
  }
  for (int i = tid; i < Nz*Wz; i += NT) Mg[(size_t)b*Nz*Wz+i] = s_M[i];
  if (tid < Nz){ ug[b*Nz+tid]=s_u[tid]; pg[b*Nz+tid]=s_p[tid]; wwg[b*Nz+tid]=s_ww[tid]; }
  if (tid < Nz*Nz) Lg[b*Nz*Nz+tid]=s_L[tid];
  if (tid < Rz*Nz) wrg[b*Rz*Nz+tid]=s_wr[tid];
}

__global__ void __launch_bounds__(NT, 4)
dnc_kernel(const int* __restrict__ src, const float* __restrict__ emb,
           const float* __restrict__ w_ih, const float* __restrict__ w_hh,
           const float* __restrict__ b_lstm,
           const float* __restrict__ w_xi, const float* __restrict__ b_xi,
           const float* __restrict__ w_out, const float* __restrict__ b_out,
           float* __restrict__ out, float* __restrict__ ws)
{
  __shared__ __align__(16) float s_x[2048];   // 8 KB: [emb 512 | r 1024 | h 512]

  const int tid = threadIdx.x;
  const int gid = blockIdx.x*NT + tid;

  float* embT  = ws;                       // [T][B][512]   cached RO
  float* wxiT  = ws + WXIT_OFF;            // [IF][512]     cached RO
  float* woutT = ws + WOUT_OFF;            // [512][1536]   cached RO ([h|r] cols)
  float* hT    = ws + HT_OFF;              // [2][B][512]   coherent
  float* cT    = ws + CT_OFF;              // [B][512]      cached, WG-pinned
  float* rT    = ws + RT_OFF;              // [2][B][1024]  coherent
  float* xiT   = ws + XIT_OFF;             // [B][IFz]      coherent
  float* Mg    = ws + MG_OFF;              // [B][2560]     cached, WG-pinned
  float* ug    = ws + UG_OFF;
  float* pg    = ug + Bz*Nz;
  float* wwg   = pg + Bz*Nz;
  float* Lg    = wwg + Bz*Nz;
  float* wrg   = Lg + Bz*Nz*Nz;
  unsigned* bar = (unsigned*)(ws + BAR_OFF);
  unsigned kbar = 0;

  // ---- init (R10-verbatim) ----
  {
    float4* embT4 = (float4*)embT;
    const float4* emb4 = (const float4*)emb;
    for (int i = gid; i < Tz*Bz*128; i += NTH){
      int kg = i & 127, b = (i>>7) & 31, tt = i >> 12;
      embT4[i] = emb4[(size_t)src[b*Tz+tt]*128 + kg];
    }
  }
  for (size_t i = gid; i < (size_t)IFz*Hz; i += NTH){
    int k = (int)(i % Hz); size_t f = i / Hz;
    wxiT[i] = w_xi[(size_t)k*IFz + f];
  }
  for (size_t i = gid; i < (size_t)Hz*XD; i += NTH){
    int k = (int)(i % XD); int j = (int)(i / XD);
    woutT[i] = w_out[(size_t)k*Hz + j];
  }
  for (int i = gid; i < 2*HTB; i += NTH) hT[i]=0.f;
  for (int i = gid; i < HTB;   i += NTH) cT[i]=0.f;
  for (int i = gid; i < 2*RTB; i += NTH) rT[i]=0.f;
  for (int i = gid; i < Bz*Nz*Wz;i += NTH) Mg[i]=0.f;
  for (int i = gid; i < Bz*(3*Nz + Nz*Nz + Rz*Nz); i += NTH) ug[i]=0.f;
  gbar_fence(bar, kbar); kbar++;

  const int b  = blockIdx.x >> 3;   // 0..31  batch
  const int jc = blockIdx.x & 7;    // 0..7   row-chunk (== XCD id -> weight pinning)

  // ---- time loop (no agent fences inside) ----
  for (int t = 0; t < Tz; ++t){
    const int cur = t & 1, nxt = (t+1)&1;

    // ===== Phase A: gates GEMV (strided K-split-4) + fused out(t-1) (strided 16) =====
    {
      const float* hsrc = hT + (size_t)cur*HTB + (size_t)b*Hz;
      const float* rsrc = rT + (size_t)cur*RTB + (size_t)b*RWz;
      const float* esrc = embT + ((size_t)t*Bz + b)*Hz;
      // s_x = [emb 0:512 | r 512:1536 | h 1536:2048]
      if (tid < 256)       stage64(s_x + 1536 + tid*2, hsrc + tid*2);
      else if (tid < 768)  stage64(s_x + 512 + (tid-256)*2, rsrc + (tid-256)*2);
      else if (tid < 896){ int u = tid - 768;
        *(float4*)(s_x + u*4) = *(const float4*)(esrc + u*4);
      }
      __syncthreads();

      // gates: tid = jj(6b) | gate(2b) | ks(2b). Strided slice: elems ks*4 + i*16.
      {
        const int ks   = tid & 3;
        const int gate = (tid >> 2) & 3;
        const int jj   = tid >> 4;         // 0..63
        const int j    = jc*64 + jj;
        const int row  = gate*Hz + j;
        float acc = dotS(s_x + ks*4,        w_ih + (size_t)row*XD + ks*4, 96, 16)  // [emb|r]·w_ih
                  + dotS(s_x + 1536 + ks*4, w_hh + (size_t)row*Hz + ks*4, 32, 16); // h·w_hh
        acc += __shfl_xor(acc, 1, 64);
        acc += __shfl_xor(acc, 2, 64);
        acc += b_lstm[row];
        const int lane = tid & 63;
        const int base = lane & ~12;       // zero gate bits
        float gi = __shfl(acc, base+0,  64);
        float gf = __shfl(acc, base+4,  64);
        float gg = __shfl(acc, base+8,  64);
        float go = __shfl(acc, base+12, 64);
        if ((lane & 15) == 0){             // ks==0 && gate==0
          float cv = cT[(size_t)b*Hz + j];
          float cn = sigf(gf)*cv + sigf(gi)*tanhf(gg);
          float hn = sigf(go)*tanhf(cn);
          cT[(size_t)b*Hz + j] = cn;
          st32cv(&hT[(size_t)nxt*HTB + (size_t)b*Hz + j], hn);
        }
      }

      // fused out(t-1): [h|r]·wout_row, 16-way strided: elems oks*4 + i*64.
      if (t > 0){
        const int oks = tid & 15;
        const int ojj = tid >> 4;          // 0..63
        const int oj  = jc*64 + ojj;
        const float* wo = woutT + (size_t)oj*XD + oks*4;
        const float* xh = s_x + 1536 + oks*4;   // logical k<512 -> h
        const float* xr = s_x + oks*4;          // logical k>=512 -> s_x[k] (r at 512+)
        float a0=0.f,a1=0.f,a2=0.f,a3=0.f;
        #pragma unroll 8
        for (int i=0;i<8;i++){
          float4 xv = *(const float4*)(xh + i*64);
          float4 wv = *(const float4*)(wo + i*64);
          a0=fmaf(xv.x,wv.x,a0); a1=fmaf(xv.y,wv.y,a1);
          a2=fmaf(xv.z,wv.z,a2); a3=fmaf(xv.w,wv.w,a3);
        }
        #pragma unroll 8
        for (int i=8;i<24;i++){
          float4 xv = *(const float4*)(xr + i*64);
          float4 wv = *(const float4*)(wo + i*64);
          a0=fmaf(xv.x,wv.x,a0); a1=fmaf(xv.y,wv.y,a1);
          a2=fmaf(xv.z,wv.z,a2); a3=fmaf(xv.w,wv.w,a3);
        }
        float oa = (a0+a1)+(a2+a3);
        oa += __shfl_xor(oa, 1, 64);
        oa += __shfl_xor(oa, 2, 64);
        oa += __shfl_xor(oa, 4, 64);
        oa += __shfl_xor(oa, 8, 64);
        if (oks == 0)
          out[(size_t)b*Tz*Hz + (size_t)(t-1)*Hz + oj] = oa + b_out[oj];
      }
    }
    gbar_nf(bar, kbar); kbar++;

    // ===== Phase B: xi = h_new @ w_xi (strided K-split-4) =====
    {
      if (tid < 256) stage64(s_x + tid*2, hT + (size_t)nxt*HTB + (size_t)b*Hz + tid*2);
      __syncthreads();
      const int ks  = tid & 3;
      const int fi0 = tid >> 2;            // 0..255
      #pragma unroll
      for (int round = 0; round < 2; ++round){
        int fi = round*256 + fi0;
        int f  = jc*322 + fi;
        bool ok = (fi < 322) && (f < IFz);
        int fr = ok ? f : 0;
        float acc = dotS(s_x + ks*4, wxiT + (size_t)fr*Hz + ks*4, 32, 16);
        acc += __shfl_xor(acc, 1, 64);
        acc += __shfl_xor(acc, 2, 64);
        if (ok && ks == 0)
          st32cv(&xiT[(size_t)b*IFz + f], acc + b_xi[f]);
      }
    }
    gbar_nf(bar, kbar); kbar++;

    // ===== Phase C: memops only (1 WG per batch, spread over XCDs) =====
    if (jc == (b & 7)){
      memops(b, t, xiT, Mg, ug, pg, wwg, Lg, wrg, rT);
    }
    gbar_nf(bar, kbar); kbar++;
  }

  gbar_fence(bar, kbar); kbar++;   // make coherent state + private cT cache-readable

  // ---- epilogue: out(T-1), final h, c (state in buffer 0) ----
  if (gid < Bz*Hz){
    const int eb = gid >> 9, ej = gid & 511;
    const float* wj = woutT + (size_t)ej*XD;
    float acc = dot4c(hT + (size_t)eb*Hz,  wj,       512)
              + dot4c(rT + (size_t)eb*RWz, wj + 512, 1024)
              + b_out[ej];
    out[(size_t)eb*Tz*Hz + (size_t)(Tz-1)*Hz + ej] = acc;
    out[(size_t)Bz*Tz*Hz + (size_t)eb*Hz + ej]       = hT[(size_t)eb*Hz + ej];
    out[(size_t)Bz*Tz*Hz + HTB + (size_t)eb*Hz + ej] = cT[(size_t)eb*Hz + ej];
  }
}

extern "C" void kernel_launch(void* const* d_in, const int* in_sizes, int n_in,
                              void* d_out, int out_size, void* d_ws, size_t ws_size,
                              hipStream_t stream)
{
  const int*   src    = (const int*)  d_in[0];
  // d_in[1] = source_lengths (unused by reference)
  const float* emb    = (const float*)d_in[2];
  const float* w_ih   = (const float*)d_in[3];
  const float* w_hh   = (const float*)d_in[4];
  const float* b_lstm = (const float*)d_in[5];
  const float* w_xi   = (const float*)d_in[6];
  const float* b_xi   = (const float*)d_in[7];
  const float* w_out  = (const float*)d_in[8];
  const float* b_out  = (const float*)d_in[9];
  float* out = (float*)d_out;
  float* ws  = (float*)d_ws;

  hipMemsetAsync((char*)d_ws + (size_t)BAR_OFF*4, 0, 8192, stream);

  void* args[] = { &src, &emb, &w_ih, &w_hh, &b_lstm, &w_xi, &b_xi, &w_out, &b_out, &out, &ws };
  hipLaunchCooperativeKernel((const void*)dnc_kernel, dim3(NWG), dim3(NT), args, 0, stream);
}

// Round 13
// 17709.059 us; speedup vs baseline: 3.9141x; 1.1457x over previous
//
#include <hip/hip_runtime.h>

#define Bz 32
#define Tz 256
#define Hz 512
#define Nz 5
#define Rz 2
#define Wz 512
#define RWz 1024
#define XD 1536          // H + R*W
#define IFz 2573
#define EPSF 1e-6f
#define NWG 256
#define NT 1024
#define NTH (NWG*NT)     // 262144

#define HTB (Bz*Hz)      // 16384 floats per h buffer
#define RTB (Bz*RWz)     // 32768 floats per r buffer

// workspace float offsets (same as R10/R11 runs)
#define WXIT_OFF (Tz*Bz*Hz)                            // 4194304
#define WOUT_OFF (WXIT_OFF + IFz*Hz)                   // 5511680
#define HT_OFF   (WOUT_OFF + Hz*XD)                    // 6298112
#define CT_OFF   (HT_OFF + 2*HTB)                      // 6330880
#define RT_OFF   (CT_OFF + HTB)                        // 6347264
#define XIT_OFF  (RT_OFF + 2*RTB)                      // 6412800
#define MG_OFF   (XIT_OFF + IFz*Bz)                    // 6495136
#define UG_OFF   (MG_OFF + Bz*Nz*Wz)                   // 6577056
#define BAR_OFF  (UG_OFF + 1600 + 32)                  // 6578688 (64-aligned)

// xi field offsets
#define O_KR 0
#define O_BR 1024
#define O_KW 1026
#define O_BW 1538
#define O_E  1539
#define O_V  2051
#define O_FG 2563
#define O_GA 2565
#define O_GW 2566
#define O_PI 2567

typedef unsigned long long u64;

__device__ __forceinline__ float sigf(float x){ return 1.0f/(1.0f+expf(-x)); }
__device__ __forceinline__ float splus(float x){ return fmaxf(x,0.0f) + log1pf(expf(-fabsf(x))); }

// coherent accessors (proven R7/R9/R10/R11)
__device__ __forceinline__ void stage64(float* dst_lds, const float* src){
  u64 v = __hip_atomic_load((const u64*)src, __ATOMIC_RELAXED, __HIP_MEMORY_SCOPE_AGENT);
  *(u64*)dst_lds = v;
}
__device__ __forceinline__ float ld32cv(const float* p){
  return __hip_atomic_load(p, __ATOMIC_RELAXED, __HIP_MEMORY_SCOPE_AGENT);
}
__device__ __forceinline__ void st32cv(float* p, float v){
  __hip_atomic_store(p, v, __ATOMIC_RELAXED, __HIP_MEMORY_SCOPE_AGENT);
}

// ---- grid barriers (verbatim from R10/R11 runs) ----
__device__ __forceinline__ void gbar_fence(unsigned* bar, unsigned k){
  __syncthreads();
  const int tid = threadIdx.x;
  const unsigned wg = blockIdx.x;
  if (tid == 0){
    __builtin_amdgcn_fence(__ATOMIC_RELEASE, "agent");
    __hip_atomic_fetch_add(&bar[(wg & 15u)*64], 1u, __ATOMIC_RELAXED, __HIP_MEMORY_SCOPE_AGENT);
  }
  if (wg == 0){
    if (tid < 16){
      const unsigned tgt = (NWG/16u)*(k+1u);
      while (__hip_atomic_load(&bar[tid*64], __ATOMIC_RELAXED, __HIP_MEMORY_SCOPE_AGENT) < tgt)
        __builtin_amdgcn_s_sleep(1);
    }
    __syncthreads();
    if (tid < 16){
      __builtin_amdgcn_fence(__ATOMIC_ACQ_REL, "agent");
      __hip_atomic_store(&bar[1024 + tid*64], k+1u, __ATOMIC_RELAXED, __HIP_MEMORY_SCOPE_AGENT);
    }
    __syncthreads();
  } else {
    if (tid == 0){
      while (__hip_atomic_load(&bar[1024 + (wg & 15u)*64], __ATOMIC_RELAXED, __HIP_MEMORY_SCOPE_AGENT) < k+1u)
        __builtin_amdgcn_s_sleep(1);
      __builtin_amdgcn_fence(__ATOMIC_ACQUIRE, "agent");
    }
    __syncthreads();
  }
}
__device__ __forceinline__ void gbar_nf(unsigned* bar, unsigned k){
  __syncthreads();
  const int tid = threadIdx.x;
  const unsigned wg = blockIdx.x;
  if (tid == 0){
    asm volatile("s_waitcnt vmcnt(0) lgkmcnt(0)" ::: "memory");
    __hip_atomic_fetch_add(&bar[(wg & 15u)*64], 1u, __ATOMIC_RELAXED, __HIP_MEMORY_SCOPE_AGENT);
  }
  if (wg == 0){
    if (tid < 16){
      const unsigned tgt = (NWG/16u)*(k+1u);
      while (__hip_atomic_load(&bar[tid*64], __ATOMIC_RELAXED, __HIP_MEMORY_SCOPE_AGENT) < tgt)
        __builtin_amdgcn_s_sleep(1);
    }
    __syncthreads();
    if (tid < 16)
      __hip_atomic_store(&bar[1024 + tid*64], k+1u, __ATOMIC_RELAXED, __HIP_MEMORY_SCOPE_AGENT);
    __syncthreads();
  } else {
    if (tid == 0){
      while (__hip_atomic_load(&bar[1024 + (wg & 15u)*64], __ATOMIC_RELAXED, __HIP_MEMORY_SCOPE_AGENT) < k+1u)
        __builtin_amdgcn_s_sleep(1);
    }
    __syncthreads();
  }
}

// contiguous · contiguous dot (epilogue)
__device__ __forceinline__ float dot4c(const float* __restrict__ x,
                                       const float* __restrict__ w, int n){
  const float4* x4 = (const float4*)x;
  const float4* w4 = (const float4*)w;
  float a0=0.f,a1=0.f,a2=0.f,a3=0.f;
  #pragma unroll 8
  for (int i=0;i<n/4;i++){
    float4 xv=x4[i], wv=w4[i];
    a0=fmaf(xv.x,wv.x,a0); a1=fmaf(xv.y,wv.y,a1);
    a2=fmaf(xv.z,wv.z,a2); a3=fmaf(xv.w,wv.w,a3);
  }
  return (a0+a1)+(a2+a3);
}
// strided dot: float4 at stride `strf` floats (x and w pre-offset by lane slice)
__device__ __forceinline__ float dotS(const float* x, const float* __restrict__ w,
                                      int iters, int strf){
  float a0=0.f,a1=0.f,a2=0.f,a3=0.f;
  #pragma unroll 16
  for (int i=0;i<iters;i++){
    float4 xv = *(const float4*)(x + (size_t)i*strf);
    float4 wv = *(const float4*)(w + (size_t)i*strf);
    a0=fmaf(xv.x,wv.x,a0); a1=fmaf(xv.y,wv.y,a1);
    a2=fmaf(xv.z,wv.z,a2); a3=fmaf(xv.w,wv.w,a3);
  }
  return (a0+a1)+(a2+a3);
}

__device__ void memops(int b, int t, const float* xiT,
                       float* Mg, float* ug, float* pg, float* wwg, float* Lg, float* wrg,
                       float* rT)
{
  __shared__ float s_xi[IFz];
  __shared__ float s_M[Nz*Wz];
  __shared__ float s_u[Nz], s_p[Nz], s_ww[Nz], s_a[Nz], s_L[Nz*Nz], s_wr[Rz*Nz];
  __shared__ float s_sc[13];
  __shared__ float s_m2[Nz], s_dt[Nz], s_d0[Nz], s_d1[Nz];
  __shared__ float s_kw2, s_kr2[2];
  __shared__ float s_fwd[Rz*Nz], s_bwd[Rz*Nz];

  const int tid = threadIdx.x;
  const int wv = tid >> 6, ln = tid & 63;

  for (int f = tid; f < IFz; f += NT) s_xi[f] = ld32cv(&xiT[(size_t)b*IFz + f]);
  for (int i = tid; i < Nz*Wz; i += NT) s_M[i] = Mg[(size_t)b*Nz*Wz + i];
  if (tid < Nz){ s_u[tid]=ug[b*Nz+tid]; s_p[tid]=pg[b*Nz+tid]; s_ww[tid]=wwg[b*Nz+tid]; }
  if (tid < Nz*Nz) s_L[tid] = Lg[b*Nz*Nz+tid];
  if (tid < Rz*Nz) s_wr[tid] = wrg[b*Rz*Nz+tid];
  __syncthreads();

  if (tid == 0){
    s_sc[0] = 1.0f + splus(s_xi[O_BR+0]);
    s_sc[1] = 1.0f + splus(s_xi[O_BR+1]);
    s_sc[2] = 1.0f + splus(s_xi[O_BW]);
    s_sc[3] = sigf(s_xi[O_FG+0]);
    s_sc[4] = sigf(s_xi[O_FG+1]);
    s_sc[5] = sigf(s_xi[O_GA]);
    s_sc[6] = sigf(s_xi[O_GW]);
    for (int r=0;r<Rz;r++){
      float x0=s_xi[O_PI+r*3+0], x1=s_xi[O_PI+r*3+1], x2=s_xi[O_PI+r*3+2];
      float m = fmaxf(x0,fmaxf(x1,x2));
      float e0=expf(x0-m), e1=expf(x1-m), e2=expf(x2-m);
      float s = e0+e1+e2;
      s_sc[7+r*3+0]=e0/s; s_sc[7+r*3+1]=e1/s; s_sc[7+r*3+2]=e2/s;
    }
  }
  __syncthreads();

  if (tid < Nz){
    float psi = (1.0f - s_sc[3]*s_wr[0*Nz+tid]) * (1.0f - s_sc[4]*s_wr[1*Nz+tid]);
    float uu = s_u[tid], w = s_ww[tid];
    s_u[tid] = (uu + w - uu*w) * psi;
  }

  // cosine(M_old, kw)
  if (wv < 4){
    const int n = wv;
    float pd=0.f, pm=0.f;
    for (int w = ln; w < Wz; w += 64){
      float kv = s_xi[O_KW+w], mv = s_M[n*Wz+w];
      pd = fmaf(kv,mv,pd); pm = fmaf(mv,mv,pm);
    }
    for (int off=32; off; off>>=1){ pd += __shfl_down(pd,off,64); pm += __shfl_down(pm,off,64); }
    if (ln==0){ s_dt[n]=pd; s_m2[n]=pm; }
  }
  if (wv == 3){
    float p2=0.f;
    for (int w=ln; w<Wz; w+=64){ float kv=s_xi[O_KW+w]; p2=fmaf(kv,kv,p2); }
    for (int off=32; off; off>>=1) p2 += __shfl_down(p2,off,64);
    if (ln==0) s_kw2 = p2;
  }
  __syncthreads();
  if (wv == 0){
    const int n = 4;
    float pd=0.f, pm=0.f;
    for (int w = ln; w < Wz; w += 64){
      float kv = s_xi[O_KW+w], mv = s_M[n*Wz+w];
      pd = fmaf(kv,mv,pd); pm = fmaf(mv,mv,pm);
    }
    for (int off=32; off; off>>=1){ pd += __shfl_down(pd,off,64); pm += __shfl_down(pm,off,64); }
    if (ln==0){ s_dt[n]=pd; s_m2[n]=pm; }
  }
  __syncthreads();

  if (tid == 0){
    float su[Nz]; int idx[Nz];
    for (int i=0;i<Nz;i++){
      float v = EPSF + (1.0f-EPSF)*s_u[i];
      int j=i;
      while (j>0 && su[j-1] > v){ su[j]=su[j-1]; idx[j]=idx[j-1]; j--; }
      su[j]=v; idx[j]=i;
    }
    float cp = 1.0f;
    for (int k=0;k<Nz;k++){ s_a[idx[k]] = (1.0f - su[k])*cp; cp *= su[k]; }
    float rk = rsqrtf(s_kw2 + EPSF);
    float lg[Nz], mx=-1e30f;
    for (int n=0;n<Nz;n++){ lg[n] = s_sc[2]*s_dt[n]*rk*rsqrtf(s_m2[n]+EPSF); mx=fmaxf(mx,lg[n]); }
    float ssum=0.f;
    for (int n=0;n<Nz;n++){ lg[n]=expf(lg[n]-mx); ssum+=lg[n]; }
    float ga=s_sc[5], gw=s_sc[6];
    for (int n=0;n<Nz;n++){ float cwn = lg[n]/ssum; s_ww[n] = gw*(ga*s_a[n] + (1.0f-ga)*cwn); }
  }
  __syncthreads();

  for (int i = tid; i < Nz*Wz; i += NT){
    int n = i >> 9, w = i & 511;
    float e = sigf(s_xi[O_E+w]);
    float v = s_xi[O_V+w];
    s_M[i] = s_M[i]*(1.0f - s_ww[n]*e) + s_ww[n]*v;
  }
  __syncthreads();

  if (tid == 0){
    float wsum = 0.f;
    for (int n=0;n<Nz;n++) wsum += s_ww[n];
    float Lo[Nz*Nz];
    for (int i=0;i<Nz;i++)
      for (int j=0;j<Nz;j++)
        Lo[i*Nz+j] = (i==j) ? 0.0f : ((1.0f - s_ww[i] - s_ww[j])*s_L[i*Nz+j] + s_ww[i]*s_p[j]);
    for (int i=0;i<Nz*Nz;i++) s_L[i]=Lo[i];
    for (int j=0;j<Nz;j++) s_p[j] = (1.0f-wsum)*s_p[j] + s_ww[j];
    for (int r=0;r<Rz;r++)
      for (int n=0;n<Nz;n++){
        float f=0.f, bb=0.f;
        for (int m=0;m<Nz;m++){ f = fmaf(s_L[n*Nz+m], s_wr[r*Nz+m], f); bb = fmaf(s_L[m*Nz+n], s_wr[r*Nz+m], bb); }
        s_fwd[r*Nz+n]=f; s_bwd[r*Nz+n]=bb;
      }
  }
  __syncthreads();

  // cosine(M_new, kr)
  if (wv < 4){
    const int n = wv;
    float pm=0.f,p0=0.f,p1=0.f;
    for (int w=ln; w<Wz; w+=64){
      float mv=s_M[n*Wz+w];
      pm=fmaf(mv,mv,pm);
      p0=fmaf(s_xi[O_KR+w],    mv,p0);
      p1=fmaf(s_xi[O_KR+Wz+w], mv,p1);
    }
    for (int off=32; off; off>>=1){
      pm += __shfl_down(pm,off,64); p0 += __shfl_down(p0,off,64); p1 += __shfl_down(p1,off,64);
    }
    if (ln==0){ s_m2[n]=pm; s_d0[n]=p0; s_d1[n]=p1; }
  }
  __syncthreads();
  if (wv == 0){
    const int n = 4;
    float pm=0.f,p0=0.f,p1=0.f;
    for (int w=ln; w<Wz; w+=64){
      float mv=s_M[n*Wz+w];
      pm=fmaf(mv,mv,pm);
      p0=fmaf(s_xi[O_KR+w],    mv,p0);
      p1=fmaf(s_xi[O_KR+Wz+w], mv,p1);
    }
    for (int off=32; off; off>>=1){
      pm += __shfl_down(pm,off,64); p0 += __shfl_down(p0,off,64); p1 += __shfl_down(p1,off,64);
    }
    if (ln==0){ s_m2[n]=pm; s_d0[n]=p0; s_d1[n]=p1; }
  } else if (wv == 1 || wv == 2){
    const int r = wv - 1;
    float p2=0.f;
    for (int w=ln; w<Wz; w+=64){ float kv=s_xi[O_KR+r*Wz+w]; p2=fmaf(kv,kv,p2); }
    for (int off=32; off; off>>=1) p2 += __shfl_down(p2,off,64);
    if (ln==0) s_kr2[r]=p2;
  }
  __syncthreads();

  if (tid == 0){
    for (int r=0;r<Rz;r++){
      float rk = rsqrtf(s_kr2[r]+EPSF);
      const float* dd = (r==0) ? s_d0 : s_d1;
      float br = s_sc[r];
      float lg[Nz], mx=-1e30f;
      for (int n=0;n<Nz;n++){ lg[n] = br*dd[n]*rk*rsqrtf(s_m2[n]+EPSF); mx=fmaxf(mx,lg[n]); }
      float ssum=0.f;
      for (int n=0;n<Nz;n++){ lg[n]=expf(lg[n]-mx); ssum+=lg[n]; }
      for (int n=0;n<Nz;n++){
        float crn = lg[n]/ssum;
        s_wr[r*Nz+n] = s_sc[7+r*3+0]*s_bwd[r*Nz+n] + s_sc[7+r*3+1]*crn + s_sc[7+r*3+2]*s_fwd[r*Nz+n];
      }
    }
  }
  __syncthreads();

  // read vectors -> rT[nxt][b][r*512+w] (coherent) + private state (cached)
  float* rdst = rT + (size_t)((t+1)&1)*RTB + (size_t)b*RWz;
  for (int w = tid; w < Wz; w += NT){
    float m0=s_M[0*Wz+w], m1=s_M[1*Wz+w], m2=s_M[2*Wz+w], m3=s_M[3*Wz+w], m4=s_M[4*Wz+w];
    #pragma unroll
    for (int r=0;r<Rz;r++){
      float rv = s_wr[r*Nz+0]*m0 + s_wr[r*Nz+1]*m1 + s_wr[r*Nz+2]*m2
               + s_wr[r*Nz+3]*m3 + s_wr[r*Nz+4]*m4;
      st32cv(&rdst[r*Wz + w], rv);
    }
  }
  for (int i = tid; i < Nz*Wz; i += NT) Mg[(size_t)b*Nz*Wz+i] = s_M[i];
  if (tid < Nz){ ug[b*Nz+tid]=s_u[tid]; pg[b*Nz+tid]=s_p[tid]; wwg[b*Nz+tid]=s_ww[tid]; }
  if (tid < Nz*Nz) Lg[b*Nz*Nz+tid]=s_L[tid];
  if (tid < Rz*Nz) wrg[b*Rz*Nz+tid]=s_wr[tid];
}

__global__ void __launch_bounds__(NT, 4)
dnc_kernel(const int* __restrict__ src, const float* __restrict__ emb,
           const float* __restrict__ w_ih, const float* __restrict__ w_hh,
           const float* __restrict__ b_lstm,
           const float* __restrict__ w_xi, const float* __restrict__ b_xi,
           const float* __restrict__ w_out, const float* __restrict__ b_out,
           float* __restrict__ out, float* __restrict__ ws)
{
  __shared__ __align__(16) float s_x[4096];   // 16 KB: 2 batches x [emb 512 | r 1024 | h 512]

  const int tid = threadIdx.x;
  const int gid = blockIdx.x*NT + tid;

  float* embT  = ws;                       // [T][B][512]   cached RO
  float* wxiT  = ws + WXIT_OFF;            // [IF][512]     cached RO
  float* woutT = ws + WOUT_OFF;            // [512][1536]   cached RO ([h|r] cols)
  float* hT    = ws + HT_OFF;              // [2][B][512]   coherent
  float* cT    = ws + CT_OFF;              // [B][512]      cached, WG-pinned
  float* rT    = ws + RT_OFF;              // [2][B][1024]  coherent
  float* xiT   = ws + XIT_OFF;             // [B][IFz]      coherent
  float* Mg    = ws + MG_OFF;              // [B][2560]     cached, WG-pinned
  float* ug    = ws + UG_OFF;
  float* pg    = ug + Bz*Nz;
  float* wwg   = pg + Bz*Nz;
  float* Lg    = wwg + Bz*Nz;
  float* wrg   = Lg + Bz*Nz*Nz;
  unsigned* bar = (unsigned*)(ws + BAR_OFF);
  unsigned kbar = 0;

  // ---- init (R11-verbatim) ----
  {
    float4* embT4 = (float4*)embT;
    const float4* emb4 = (const float4*)emb;
    for (int i = gid; i < Tz*Bz*128; i += NTH){
      int kg = i & 127, b = (i>>7) & 31, tt = i >> 12;
      embT4[i] = emb4[(size_t)src[b*Tz+tt]*128 + kg];
    }
  }
  for (size_t i = gid; i < (size_t)IFz*Hz; i += NTH){
    int k = (int)(i % Hz); size_t f = i / Hz;
    wxiT[i] = w_xi[(size_t)k*IFz + f];
  }
  for (size_t i = gid; i < (size_t)Hz*XD; i += NTH){
    int k = (int)(i % XD); int j = (int)(i / XD);
    woutT[i] = w_out[(size_t)k*Hz + j];
  }
  for (int i = gid; i < 2*HTB; i += NTH) hT[i]=0.f;
  for (int i = gid; i < HTB;   i += NTH) cT[i]=0.f;
  for (int i = gid; i < 2*RTB; i += NTH) rT[i]=0.f;
  for (int i = gid; i < Bz*Nz*Wz;i += NTH) Mg[i]=0.f;
  for (int i = gid; i < Bz*(3*Nz + Nz*Nz + Rz*Nz); i += NTH) ug[i]=0.f;
  gbar_fence(bar, kbar); kbar++;

  // WG decomposition: jc (XCD pin) x sj (j-half) x bp (batch pair)
  const int jc = blockIdx.x & 7;          // 0..7
  const int sj = (blockIdx.x >> 3) & 1;   // 0..1
  const int bp = blockIdx.x >> 4;         // 0..15
  const int b0 = 2*bp;                    // batches b0, b0+1
  const int jbase = jc*64 + sj*32;        // 32 j-rows per WG

  // ---- time loop (no agent fences inside) ----
  for (int t = 0; t < Tz; ++t){
    const int cur = t & 1, nxt = (t+1)&1;

    // ===== Phase A: gates GEMV (strided ks-4) + fused out(t-1) (strided 16), 2 batches =====
    {
      // stage per-batch [emb 0:512 | r 512:1536 | h 1536:2048] at s_x + bl*2048
      for (int u = tid; u < 1792; u += NT){
        const int bl = (u >= 896) ? 1 : 0;
        const int v  = u - bl*896;
        const int b  = b0 + bl;
        float* dst = s_x + bl*2048;
        if (v < 256)
          stage64(dst + 1536 + v*2, hT + (size_t)cur*HTB + (size_t)b*Hz + v*2);
        else if (v < 768)
          stage64(dst + 512 + (v-256)*2, rT + (size_t)cur*RTB + (size_t)b*RWz + (v-256)*2);
        else
          *(float4*)(dst + (v-768)*4) =
            *(const float4*)(embT + ((size_t)t*Bz + b)*Hz + (v-768)*4);
      }
      __syncthreads();

      // gates: tid = jj(5b) | bl(1b) | gate(2b) | ks(2b)
      {
        const int ks   = tid & 3;
        const int gate = (tid >> 2) & 3;
        const int bl   = (tid >> 4) & 1;
        const int jj   = tid >> 5;         // 0..31
        const int j    = jbase + jj;
        const int row  = gate*Hz + j;
        const float* xb = s_x + bl*2048;
        float acc = dotS(xb + ks*4,        w_ih + (size_t)row*XD + ks*4, 96, 16)  // [emb|r]·w_ih
                  + dotS(xb + 1536 + ks*4, w_hh + (size_t)row*Hz + ks*4, 32, 16); // h·w_hh
        acc += __shfl_xor(acc, 1, 64);
        acc += __shfl_xor(acc, 2, 64);
        acc += b_lstm[row];
        const int lane = tid & 63;
        const int base = lane & ~12;       // zero gate bits [2:3]
        float gi = __shfl(acc, base+0,  64);
        float gf = __shfl(acc, base+4,  64);
        float gg = __shfl(acc, base+8,  64);
        float go = __shfl(acc, base+12, 64);
        if ((lane & 15) == 0){             // ks==0 && gate==0
          const int b = b0 + bl;
          float cv = cT[(size_t)b*Hz + j];
          float cn = sigf(gf)*cv + sigf(gi)*tanhf(gg);
          float hn = sigf(go)*tanhf(cn);
          cT[(size_t)b*Hz + j] = cn;
          st32cv(&hT[(size_t)nxt*HTB + (size_t)b*Hz + j], hn);
        }
      }

      // fused out(t-1): tid = ojj(5b) | bl(1b) | oks(4b); [h|r]·wout strided-16
      if (t > 0){
        const int oks = tid & 15;
        const int bl  = (tid >> 4) & 1;
        const int ojj = tid >> 5;          // 0..31
        const int oj  = jbase + ojj;
        const float* xb = s_x + bl*2048;
        const float* wo = woutT + (size_t)oj*XD + oks*4;
        const float* xh = xb + 1536 + oks*4;   // logical k<512 -> h
        const float* xr = xb + oks*4;          // logical k in [512,1536): s_x[k] = r
        float a0=0.f,a1=0.f,a2=0.f,a3=0.f;
        #pragma unroll 8
        for (int i=0;i<8;i++){
          float4 xv = *(const float4*)(xh + i*64);
          float4 wv = *(const float4*)(wo + i*64);
          a0=fmaf(xv.x,wv.x,a0); a1=fmaf(xv.y,wv.y,a1);
          a2=fmaf(xv.z,wv.z,a2); a3=fmaf(xv.w,wv.w,a3);
        }
        #pragma unroll 16
        for (int i=8;i<24;i++){
          float4 xv = *(const float4*)(xr + i*64);
          float4 wv = *(const float4*)(wo + i*64);
          a0=fmaf(xv.x,wv.x,a0); a1=fmaf(xv.y,wv.y,a1);
          a2=fmaf(xv.z,wv.z,a2); a3=fmaf(xv.w,wv.w,a3);
        }
        float oa = (a0+a1)+(a2+a3);
        oa += __shfl_xor(oa, 1, 64);
        oa += __shfl_xor(oa, 2, 64);
        oa += __shfl_xor(oa, 4, 64);
        oa += __shfl_xor(oa, 8, 64);
        if (oks == 0)
          out[(size_t)(b0+bl)*Tz*Hz + (size_t)(t-1)*Hz + oj] = oa + b_out[oj];
      }
    }
    gbar_nf(bar, kbar); kbar++;

    // ===== Phase B: xi = h_new @ w_xi (strided ks-4), 2 batches =====
    {
      if (tid < 512){
        const int bl = tid >> 8, v = tid & 255;
        stage64(s_x + bl*2048 + v*2, hT + (size_t)nxt*HTB + (size_t)(b0+bl)*Hz + v*2);
      }
      __syncthreads();
      const int ks  = tid & 3;
      const int bl  = (tid >> 2) & 1;
      const int fi0 = tid >> 3;            // 0..127
      #pragma unroll
      for (int round = 0; round < 2; ++round){
        int fi = round*128 + fi0;          // 0..255 (need 0..160)
        int f  = jc*322 + sj*161 + fi;
        bool ok = (fi < 161) && (f < IFz);
        int fr = ok ? f : 0;
        float acc = dotS(s_x + bl*2048 + ks*4, wxiT + (size_t)fr*Hz + ks*4, 32, 16);
        acc += __shfl_xor(acc, 1, 64);
        acc += __shfl_xor(acc, 2, 64);
        if (ok && ks == 0)
          st32cv(&xiT[(size_t)(b0+bl)*IFz + f], acc + b_xi[f]);
      }
    }
    gbar_nf(bar, kbar); kbar++;

    // ===== Phase C: memops only (one WG per batch, XCD-spread) =====
    {
      const int bA = b0;       // even batch: owned by sj==0 && jc==(bA&7)
      const int bB = b0 + 1;   // odd batch:  owned by sj==1 && jc==(bB&7)
      if (sj == 0 && jc == (bA & 7))
        memops(bA, t, xiT, Mg, ug, pg, wwg, Lg, wrg, rT);
      else if (sj == 1 && jc == (bB & 7))
        memops(bB, t, xiT, Mg, ug, pg, wwg, Lg, wrg, rT);
    }
    gbar_nf(bar, kbar); kbar++;
  }

  gbar_fence(bar, kbar); kbar++;   // make coherent state + private cT cache-readable

  // ---- epilogue: out(T-1), final h, c (state in buffer 0) ----
  if (gid < Bz*Hz){
    const int eb = gid >> 9, ej = gid & 511;
    const float* wj = woutT + (size_t)ej*XD;
    float acc = dot4c(hT + (size_t)eb*Hz,  wj,       512)
              + dot4c(rT + (size_t)eb*RWz, wj + 512, 1024)
              + b_out[ej];
    out[(size_t)eb*Tz*Hz + (size_t)(Tz-1)*Hz + ej] = acc;
    out[(size_t)Bz*Tz*Hz + (size_t)eb*Hz + ej]       = hT[(size_t)eb*Hz + ej];
    out[(size_t)Bz*Tz*Hz + HTB + (size_t)eb*Hz + ej] = cT[(size_t)eb*Hz + ej];
  }
}

extern "C" void kernel_launch(void* const* d_in, const int* in_sizes, int n_in,
                              void* d_out, int out_size, void* d_ws, size_t ws_size,
                              hipStream_t stream)
{
  const int*   src    = (const int*)  d_in[0];
  // d_in[1] = source_lengths (unused by reference)
  const float* emb    = (const float*)d_in[2];
  const float* w_ih   = (const float*)d_in[3];
  const float* w_hh   = (const float*)d_in[4];
  const float* b_lstm = (const float*)d_in[5];
  const float* w_xi   = (const float*)d_in[6];
  const float* b_xi   = (const float*)d_in[7];
  const float* w_out  = (const float*)d_in[8];
  const float* b_out  = (const float*)d_in[9];
  float* out = (float*)d_out;
  float* ws  = (float*)d_ws;

  hipMemsetAsync((char*)d_ws + (size_t)BAR_OFF*4, 0, 8192, stream);

  void* args[] = { &src, &emb, &w_ih, &w_hh, &b_lstm, &w_xi, &b_xi, &w_out, &b_out, &out, &ws };
  hipLaunchCooperativeKernel((const void*)dnc_kernel, dim3(NWG), dim3(NT), args, 0, stream);
}